// Round 7
// baseline (233.449 us; speedup 1.0000x reference)
//
#include <hip/hip_runtime.h>
#include <hip/hip_fp16.h>

#define NN 50000
#define NE 800000

typedef unsigned short u16;

__device__ __forceinline__ float wave_sum64(float p) {
  #pragma unroll
  for (int m = 1; m <= 32; m <<= 1) p += __shfl_xor(p, m);
  return p;
}

// ---------------- K1: fused QKV + skip GEMM (jt-loop) + (y==1) histogram ----
// q stored natural [n][128] fp32.
// kv stored [n][32] x uint4: entry e = {k[4e..4e+3], v[4e..4e+3]} fp16 (16B),
// global channel g = 4e spans head0 (0..63) then head1 (64..127).
__global__ __launch_bounds__(256) void k_gemm_qkv(
    const float* __restrict__ x,
    const float* __restrict__ Wq, const float* __restrict__ bq,
    const float* __restrict__ Wk, const float* __restrict__ bk,
    const float* __restrict__ Wv, const float* __restrict__ bv,
    const float* __restrict__ Wskip, const float* __restrict__ bskip,
    const int* __restrict__ ei, int* __restrict__ cnt,
    float* __restrict__ qs, u16* __restrict__ kvp, float* __restrict__ skip)
{
  const int t = threadIdx.x;

  if (blockIdx.y == 1) {  // histogram slice
    const int e0 = blockIdx.x * 1024 + t;
    #pragma unroll
    for (int it = 0; it < 4; it++) {
      const int e = e0 + it * 256;
      if (e < NE) atomicAdd(&cnt[ei[NE + e]], 1);
    }
    return;
  }

  __shared__ float xsT[64][68];
  __shared__ float wsT[64][68];
  const int tileN = blockIdx.x * 64;

  {  // load x tile once
    const int nl = t >> 2, c0 = (t & 3) * 16;
    const int n = tileN + nl;
    float4 a0, a1, a2, a3;
    if (n < NN) {
      const float4* xr = (const float4*)(x + (size_t)n * 64 + c0);
      a0 = xr[0]; a1 = xr[1]; a2 = xr[2]; a3 = xr[3];
    } else {
      a0 = a1 = a2 = a3 = make_float4(0.f, 0.f, 0.f, 0.f);
    }
    xsT[c0 +  0][nl] = a0.x; xsT[c0 +  1][nl] = a0.y; xsT[c0 +  2][nl] = a0.z; xsT[c0 +  3][nl] = a0.w;
    xsT[c0 +  4][nl] = a1.x; xsT[c0 +  5][nl] = a1.y; xsT[c0 +  6][nl] = a1.z; xsT[c0 +  7][nl] = a1.w;
    xsT[c0 +  8][nl] = a2.x; xsT[c0 +  9][nl] = a2.y; xsT[c0 + 10][nl] = a2.z; xsT[c0 + 11][nl] = a2.w;
    xsT[c0 + 12][nl] = a3.x; xsT[c0 + 13][nl] = a3.y; xsT[c0 + 14][nl] = a3.z; xsT[c0 + 15][nl] = a3.w;
  }

  const int tx = t & 15, ty = t >> 4;

  for (int jt = 0; jt < 7; jt++) {
    const float* W; const float* bias; int rowbase;
    if (jt < 2)      { W = Wq;    bias = bq;    rowbase = jt * 64; }
    else if (jt < 4) { W = Wk;    bias = bk;    rowbase = (jt - 2) * 64; }
    else if (jt < 6) { W = Wv;    bias = bv;    rowbase = (jt - 4) * 64; }
    else             { W = Wskip; bias = bskip; rowbase = 0; }

    __syncthreads();  // previous MAC done (and xsT ready on first iter)
    {
      const int nl = t >> 2, c0 = (t & 3) * 16;
      const float4* wr = (const float4*)(W + (size_t)(rowbase + nl) * 64 + c0);
      float4 b0 = wr[0], b1 = wr[1], b2 = wr[2], b3 = wr[3];
      wsT[c0 +  0][nl] = b0.x; wsT[c0 +  1][nl] = b0.y; wsT[c0 +  2][nl] = b0.z; wsT[c0 +  3][nl] = b0.w;
      wsT[c0 +  4][nl] = b1.x; wsT[c0 +  5][nl] = b1.y; wsT[c0 +  6][nl] = b1.z; wsT[c0 +  7][nl] = b1.w;
      wsT[c0 +  8][nl] = b2.x; wsT[c0 +  9][nl] = b2.y; wsT[c0 + 10][nl] = b2.z; wsT[c0 + 11][nl] = b2.w;
      wsT[c0 + 12][nl] = b3.x; wsT[c0 + 13][nl] = b3.y; wsT[c0 + 14][nl] = b3.z; wsT[c0 + 15][nl] = b3.w;
    }
    __syncthreads();

    float acc[4][4];
    #pragma unroll
    for (int i = 0; i < 4; i++)
      #pragma unroll
      for (int j = 0; j < 4; j++) acc[i][j] = 0.f;

    #pragma unroll 8
    for (int kk = 0; kk < 64; kk++) {
      float4 a = *(const float4*)&xsT[kk][tx * 4];
      float4 b = *(const float4*)&wsT[kk][ty * 4];
      acc[0][0] += a.x * b.x; acc[0][1] += a.x * b.y; acc[0][2] += a.x * b.z; acc[0][3] += a.x * b.w;
      acc[1][0] += a.y * b.x; acc[1][1] += a.y * b.y; acc[1][2] += a.y * b.z; acc[1][3] += a.y * b.w;
      acc[2][0] += a.z * b.x; acc[2][1] += a.z * b.y; acc[2][2] += a.z * b.z; acc[2][3] += a.z * b.w;
      acc[3][0] += a.w * b.x; acc[3][1] += a.w * b.y; acc[3][2] += a.w * b.z; acc[3][3] += a.w * b.w;
    }

    const int n0 = tileN + tx * 4;
    const int col0 = rowbase + ty * 4;   // 4-aligned global channel
    const float4 bb = *(const float4*)(bias + col0);
    #pragma unroll
    for (int i = 0; i < 4; i++) {
      const int n = n0 + i;
      if (n >= NN) continue;
      const float r0 = acc[i][0] + bb.x, r1 = acc[i][1] + bb.y;
      const float r2 = acc[i][2] + bb.z, r3 = acc[i][3] + bb.w;
      if (jt < 2) {
        *(float4*)(qs + (size_t)n * 128 + col0) = make_float4(r0, r1, r2, r3);
      } else if (jt < 6) {
        const int entry = col0 >> 2;             // 0..31
        __half2 h01 = __halves2half2(__float2half_rn(r0), __float2half_rn(r1));
        __half2 h23 = __halves2half2(__float2half_rn(r2), __float2half_rn(r3));
        uint2 pk;
        pk.x = *(unsigned*)&h01; pk.y = *(unsigned*)&h23;
        *(uint2*)(kvp + (size_t)n * 256 + entry * 8 + ((jt >= 4) ? 4 : 0)) = pk;
      } else {
        *(float4*)(skip + (size_t)n * 64 + col0) = make_float4(r0, r1, r2, r3);
      }
    }
  }
}

// ---------------- S2a: per-block partial sums (49 blocks x 1024) ------------
__global__ __launch_bounds__(1024) void k_scanA(const int* __restrict__ cnt, int* __restrict__ bsum) {
  __shared__ int wsum[16];
  const int t = threadIdx.x, lane = t & 63, wid = t >> 6;
  const int i = blockIdx.x * 1024 + t;
  int val = (i < NN) ? cnt[i] : 0;
  #pragma unroll
  for (int m = 1; m <= 32; m <<= 1) val += __shfl_xor(val, m);
  if (lane == 0) wsum[wid] = val;
  __syncthreads();
  if (t == 0) {
    int s = 0;
    #pragma unroll
    for (int j = 0; j < 16; j++) s += wsum[j];
    bsum[blockIdx.x] = s;
  }
}

// ---------------- S2c: local scan + (inline bsum prefix) -> rowptr ----------
__global__ __launch_bounds__(1024) void k_scanC(
    const int* __restrict__ cnt, const int* __restrict__ bsum, int* __restrict__ rowptr) {
  __shared__ int wsum[16];
  __shared__ int boff_s;
  const int t = threadIdx.x, lane = t & 63, wid = t >> 6;
  if (t < 64) {  // sum of bsum[0 .. blockIdx.x-1] with one wave
    int v = (t < blockIdx.x) ? bsum[t] : 0;
    #pragma unroll
    for (int m = 1; m <= 32; m <<= 1) v += __shfl_xor(v, m);
    if (t == 0) boff_s = v;
  }
  const int i = blockIdx.x * 1024 + t;
  const int val = (i < NN) ? cnt[i] : 0;
  int incl = val;
  #pragma unroll
  for (int off = 1; off < 64; off <<= 1) {
    int n = __shfl_up(incl, off, 64);
    if (lane >= off) incl += n;
  }
  if (lane == 63) wsum[wid] = incl;
  __syncthreads();
  if (t < 16) {
    int wv = wsum[t];
    int wincl = wv;
    #pragma unroll
    for (int off = 1; off < 16; off <<= 1) {
      int n = __shfl_up(wincl, off, 64);
      if (t >= off) wincl += n;
    }
    wsum[t] = wincl - wv;  // exclusive wave offsets
  }
  __syncthreads();
  if (i < NN) rowptr[i] = boff_s + wsum[wid] + incl - val;
  if (blockIdx.x == 0 && t == 0) rowptr[NN] = NE;
}

// ---------------- S3: bucket-fill edges sorted by dst (packed int2) ---------
// consumes cnt (atomicSub down to zero)
__global__ __launch_bounds__(256) void k_fill(
    const int* __restrict__ ei, const float* __restrict__ ea,
    const int* __restrict__ rowptr, int* __restrict__ cnt,
    int2* __restrict__ epack) {
  const int e = blockIdx.x * 256 + threadIdx.x;
  if (e < NE) {
    const int dst = ei[NE + e];
    const int p = atomicSub(&cnt[dst], 1) - 1;
    epack[rowptr[dst] + p] = make_int2(ei[e], __float_as_int(ea[e]));
  }
}

// ------- K2: per-dst softmax + agg, 2 edges per wave (half-wave each),
//         barrier-free after wlT staging; shuffle transpose; dual-moment LN --
__global__ __launch_bounds__(256) void k_fused(
    const float* __restrict__ qs, const u16* __restrict__ kvp,
    const float* __restrict__ skip, const float* __restrict__ x,
    const int* __restrict__ rowptr, const int2* __restrict__ epack,
    const float* __restrict__ We,
    const float* __restrict__ Wl, const float* __restrict__ bl,
    const float* __restrict__ g0, const float* __restrict__ b0,
    const float* __restrict__ g1, const float* __restrict__ b1,
    float* __restrict__ out)
{
  __shared__ float wlT[64][65];
  const int t = threadIdx.x;
  {
    const int jl = t >> 2, c0 = (t & 3) * 16;
    const float4* wr = (const float4*)(Wl + (size_t)jl * 64 + c0);
    float4 w0 = wr[0], w1 = wr[1], w2 = wr[2], w3 = wr[3];
    wlT[c0 +  0][jl] = w0.x; wlT[c0 +  1][jl] = w0.y; wlT[c0 +  2][jl] = w0.z; wlT[c0 +  3][jl] = w0.w;
    wlT[c0 +  4][jl] = w1.x; wlT[c0 +  5][jl] = w1.y; wlT[c0 +  6][jl] = w1.z; wlT[c0 +  7][jl] = w1.w;
    wlT[c0 +  8][jl] = w2.x; wlT[c0 +  9][jl] = w2.y; wlT[c0 + 10][jl] = w2.z; wlT[c0 + 11][jl] = w2.w;
    wlT[c0 + 12][jl] = w3.x; wlT[c0 + 13][jl] = w3.y; wlT[c0 + 14][jl] = w3.z; wlT[c0 + 15][jl] = w3.w;
  }
  __syncthreads();  // the ONLY barrier; waves independent afterwards

  const int w = t >> 6;
  const int dst = __builtin_amdgcn_readfirstlane(blockIdx.x * 4 + w);
  const int lane = t & 63;
  const int half = lane >> 5;      // which edge of the pair
  const int el = lane & 31;        // 4-channel group index (0..31 over 128 ch)

  const float4 qv = ((const float4*)(qs + (size_t)dst * 128))[el];
  const float4 we4 = ((const float4*)We)[el];

  // qwe per head: reduce over the 16-lane channel group
  float qwe = qv.x * we4.x + qv.y * we4.y + qv.z * we4.z + qv.w * we4.w;
  #pragma unroll
  for (int mm = 1; mm <= 8; mm <<= 1) qwe += __shfl_xor(qwe, mm);

  const int base = rowptr[dst];
  const int deg  = rowptr[dst + 1] - base;
  const uint4* kv4 = (const uint4*)kvp;
  const int2* ep = epack + base;

  float s = 0.f, sw = 0.f;
  float sv0 = 0.f, sv1 = 0.f, sv2 = 0.f, sv3 = 0.f;

#define PROC(u, wg, mask)                                                   \
  {                                                                         \
    const float2 k01 = __half22float2(*(const __half2*)&(u).x);             \
    const float2 k23 = __half22float2(*(const __half2*)&(u).y);             \
    const float2 v01 = __half22float2(*(const __half2*)&(u).z);             \
    const float2 v23 = __half22float2(*(const __half2*)&(u).w);             \
    float p = qv.x * k01.x + qv.y * k01.y + qv.z * k23.x + qv.w * k23.y;    \
    _Pragma("unroll")                                                       \
    for (int mm = 1; mm <= 8; mm <<= 1) p += __shfl_xor(p, mm);             \
    float e_ = __expf((p + (wg) * qwe) * 0.125f);                           \
    e_ = (mask) ? e_ : 0.f;                                                 \
    s += e_; sw += e_ * (wg);                                               \
    sv0 += e_ * v01.x; sv1 += e_ * v01.y;                                   \
    sv2 += e_ * v23.x; sv3 += e_ * v23.y;                                   \
  }

  int i = 0;
  for (; i + 8 <= deg; i += 8) {
    const int2 er0 = ep[i + half];
    const int2 er1 = ep[i + 2 + half];
    const int2 er2 = ep[i + 4 + half];
    const int2 er3 = ep[i + 6 + half];
    const uint4 u0 = kv4[(size_t)er0.x * 32 + el];
    const uint4 u1 = kv4[(size_t)er1.x * 32 + el];
    const uint4 u2 = kv4[(size_t)er2.x * 32 + el];
    const uint4 u3 = kv4[(size_t)er3.x * 32 + el];
    PROC(u0, __int_as_float(er0.y), true)
    PROC(u1, __int_as_float(er1.y), true)
    PROC(u2, __int_as_float(er2.y), true)
    PROC(u3, __int_as_float(er3.y), true)
  }
  for (; i + 4 <= deg; i += 4) {
    const int2 er0 = ep[i + half];
    const int2 er1 = ep[i + 2 + half];
    const uint4 u0 = kv4[(size_t)er0.x * 32 + el];
    const uint4 u1 = kv4[(size_t)er1.x * 32 + el];
    PROC(u0, __int_as_float(er0.y), true)
    PROC(u1, __int_as_float(er1.y), true)
  }
  for (; i < deg; i += 2) {
    const int idx = i + half;
    const bool valid = idx < deg;
    const int2 er = ep[valid ? idx : (deg - 1)];
    const uint4 u = kv4[(size_t)er.x * 32 + el];
    PROC(u, __int_as_float(er.y), valid)
  }
#undef PROC

  // combine the two half-wave partial accumulators
  s  += __shfl_xor(s, 32);
  sw += __shfl_xor(sw, 32);
  sv0 += __shfl_xor(sv0, 32); sv1 += __shfl_xor(sv1, 32);
  sv2 += __shfl_xor(sv2, 32); sv3 += __shfl_xor(sv3, 32);

  float a0 = 0.f, a1 = 0.f, a2 = 0.f, a3 = 0.f;
  if (deg > 0) {
    const float inv = 1.f / s;
    a0 = (sv0 + sw * we4.x) * inv;
    a1 = (sv1 + sw * we4.y) * inv;
    a2 = (sv2 + sw * we4.z) * inv;
    a3 = (sv3 + sw * we4.w) * inv;
  }
  // head mean: channel c of head0 (el<16) with channel c of head1 (el+16)
  a0 = 0.5f * (a0 + __shfl_xor(a0, 16));
  a1 = 0.5f * (a1 + __shfl_xor(a1, 16));
  a2 = 0.5f * (a2 + __shfl_xor(a2, 16));
  a3 = 0.5f * (a3 + __shfl_xor(a3, 16));

  // register transpose: lane c needs component (c&3) from source lane c>>2
  const int srcl = lane >> 2;
  const float r0 = __shfl(a0, srcl);
  const float r1 = __shfl(a1, srcl);
  const float r2 = __shfl(a2, srcl);
  const float r3 = __shfl(a3, srcl);
  const int sel = lane & 3;
  const float attn = (sel == 0) ? r0 : (sel == 1) ? r1 : (sel == 2) ? r2 : r3;

  const float hv = attn + skip[(size_t)dst * 64 + lane];

  // LN0 via dual moments (two independent 6-step chains)
  float m1 = hv, m2 = hv * hv;
  #pragma unroll
  for (int mm = 1; mm <= 32; mm <<= 1) {
    m1 += __shfl_xor(m1, mm);
    m2 += __shfl_xor(m2, mm);
  }
  const float mean = m1 * (1.f / 64.f);
  const float var = fmaxf(m2 * (1.f / 64.f) - mean * mean, 0.f);
  const float x1 = x[(size_t)dst * 64 + lane] + (hv - mean) * rsqrtf(var + 1e-5f) * g0[lane] + b0[lane];

  // y = x1 @ Wl^T + bl  (4 partial accumulators for ILP)
  float y0 = 0.f, y1 = 0.f, y2 = 0.f, y3 = 0.f;
  #pragma unroll
  for (int kk = 0; kk < 64; kk += 4) {
    y0 += __shfl(x1, kk)     * wlT[kk][lane];
    y1 += __shfl(x1, kk + 1) * wlT[kk + 1][lane];
    y2 += __shfl(x1, kk + 2) * wlT[kk + 2][lane];
    y3 += __shfl(x1, kk + 3) * wlT[kk + 3][lane];
  }
  const float y = bl[lane] + (y0 + y1) + (y2 + y3);

  // LN1 via dual moments
  float n1 = y, n2 = y * y;
  #pragma unroll
  for (int mm = 1; mm <= 32; mm <<= 1) {
    n1 += __shfl_xor(n1, mm);
    n2 += __shfl_xor(n2, mm);
  }
  const float mean2 = n1 * (1.f / 64.f);
  const float var2 = fmaxf(n2 * (1.f / 64.f) - mean2 * mean2, 0.f);
  out[(size_t)dst * 64 + lane] = x1 + (y - mean2) * rsqrtf(var2 + 1e-5f) * g1[lane] + b1[lane];
}

extern "C" void kernel_launch(void* const* d_in, const int* in_sizes, int n_in,
                              void* d_out, int out_size, void* d_ws, size_t ws_size,
                              hipStream_t stream) {
  const float* x     = (const float*)d_in[0];
  const int*   ei    = (const int*)d_in[1];
  const float* ea    = (const float*)d_in[2];
  const float* Wq    = (const float*)d_in[3];
  const float* bq    = (const float*)d_in[4];
  const float* Wk    = (const float*)d_in[5];
  const float* bk    = (const float*)d_in[6];
  const float* Wv    = (const float*)d_in[7];
  const float* bv    = (const float*)d_in[8];
  const float* We    = (const float*)d_in[9];
  const float* Wskip = (const float*)d_in[10];
  const float* bskip = (const float*)d_in[11];
  const float* Wl    = (const float*)d_in[12];
  const float* bl    = (const float*)d_in[13];
  const float* g0    = (const float*)d_in[14];
  const float* b0    = (const float*)d_in[15];
  const float* g1    = (const float*)d_in[16];
  const float* b1    = (const float*)d_in[17];
  float* out = (float*)d_out;

  float* ws = (float*)d_ws;
  size_t off = 0;
  float* qs   = ws + off; off += (size_t)NN * 128;
  u16* kvp    = (u16*)(ws + off); off += (size_t)NN * 128;   // 512B/node
  float* skip = ws + off; off += (size_t)NN * 64;
  int* cnt    = (int*)(ws + off); off += NN;
  int* rowptr = (int*)(ws + off); off += NN + 1;
  int* bsum   = (int*)(ws + off); off += 64;
  int2* epack = (int2*)(ws + off); off += (size_t)NE * 2;

  hipMemsetAsync(cnt, 0, (size_t)NN * sizeof(int), stream);

  dim3 gGemm((NN + 63) / 64, 2);  // y==1 -> histogram slice
  hipLaunchKernelGGL(k_gemm_qkv, gGemm, dim3(256), 0, stream,
                     x, Wq, bq, Wk, bk, Wv, bv, Wskip, bskip, ei, cnt, qs, kvp, skip);
  hipLaunchKernelGGL(k_scanA, dim3(49), dim3(1024), 0, stream, cnt, bsum);
  hipLaunchKernelGGL(k_scanC, dim3(49), dim3(1024), 0, stream, cnt, bsum, rowptr);
  hipLaunchKernelGGL(k_fill, dim3((NE + 255) / 256), dim3(256), 0, stream,
                     ei, ea, rowptr, cnt, epack);
  hipLaunchKernelGGL(k_fused, dim3(NN / 4), dim3(256), 0, stream,
                     qs, kvp, skip, x, rowptr, epack, We,
                     Wl, bl, g0, b0, g1, b1, out);
}

// Round 8
// 213.946 us; speedup vs baseline: 1.0912x; 1.0912x over previous
//
#include <hip/hip_runtime.h>
#include <hip/hip_fp16.h>

#define NN 50000
#define NE 800000

typedef unsigned short u16;
typedef float v2f __attribute__((ext_vector_type(2)));

__device__ __forceinline__ float wave_sum64(float p) {
  #pragma unroll
  for (int m = 1; m <= 32; m <<= 1) p += __shfl_xor(p, m);
  return p;
}

// ---------------- K1: fused QKV + skip GEMM (jt-loop) + (y==1) histogram ----
// q stored natural [n][128] fp32.
// kv stored [n][64] x u32 fp8-e4m3: entry e (4 channels): u32 k at idx 2e,
// u32 v at idx 2e+1. Global channel g = 4e spans head0 (0..63), head1 (64..127).
__global__ __launch_bounds__(256) void k_gemm_qkv(
    const float* __restrict__ x,
    const float* __restrict__ Wq, const float* __restrict__ bq,
    const float* __restrict__ Wk, const float* __restrict__ bk,
    const float* __restrict__ Wv, const float* __restrict__ bv,
    const float* __restrict__ Wskip, const float* __restrict__ bskip,
    const int* __restrict__ ei, int* __restrict__ cnt,
    float* __restrict__ qs, unsigned* __restrict__ kvp, float* __restrict__ skip)
{
  const int t = threadIdx.x;

  if (blockIdx.y == 1) {  // histogram slice
    const int e0 = blockIdx.x * 1024 + t;
    #pragma unroll
    for (int it = 0; it < 4; it++) {
      const int e = e0 + it * 256;
      if (e < NE) atomicAdd(&cnt[ei[NE + e]], 1);
    }
    return;
  }

  __shared__ float xsT[64][68];
  __shared__ float wsT[64][68];
  const int tileN = blockIdx.x * 64;

  {  // load x tile once
    const int nl = t >> 2, c0 = (t & 3) * 16;
    const int n = tileN + nl;
    float4 a0, a1, a2, a3;
    if (n < NN) {
      const float4* xr = (const float4*)(x + (size_t)n * 64 + c0);
      a0 = xr[0]; a1 = xr[1]; a2 = xr[2]; a3 = xr[3];
    } else {
      a0 = a1 = a2 = a3 = make_float4(0.f, 0.f, 0.f, 0.f);
    }
    xsT[c0 +  0][nl] = a0.x; xsT[c0 +  1][nl] = a0.y; xsT[c0 +  2][nl] = a0.z; xsT[c0 +  3][nl] = a0.w;
    xsT[c0 +  4][nl] = a1.x; xsT[c0 +  5][nl] = a1.y; xsT[c0 +  6][nl] = a1.z; xsT[c0 +  7][nl] = a1.w;
    xsT[c0 +  8][nl] = a2.x; xsT[c0 +  9][nl] = a2.y; xsT[c0 + 10][nl] = a2.z; xsT[c0 + 11][nl] = a2.w;
    xsT[c0 + 12][nl] = a3.x; xsT[c0 + 13][nl] = a3.y; xsT[c0 + 14][nl] = a3.z; xsT[c0 + 15][nl] = a3.w;
  }

  const int tx = t & 15, ty = t >> 4;

  for (int jt = 0; jt < 7; jt++) {
    const float* W; const float* bias; int rowbase;
    if (jt < 2)      { W = Wq;    bias = bq;    rowbase = jt * 64; }
    else if (jt < 4) { W = Wk;    bias = bk;    rowbase = (jt - 2) * 64; }
    else if (jt < 6) { W = Wv;    bias = bv;    rowbase = (jt - 4) * 64; }
    else             { W = Wskip; bias = bskip; rowbase = 0; }

    __syncthreads();  // previous MAC done (and xsT ready on first iter)
    {
      const int nl = t >> 2, c0 = (t & 3) * 16;
      const float4* wr = (const float4*)(W + (size_t)(rowbase + nl) * 64 + c0);
      float4 b0 = wr[0], b1 = wr[1], b2 = wr[2], b3 = wr[3];
      wsT[c0 +  0][nl] = b0.x; wsT[c0 +  1][nl] = b0.y; wsT[c0 +  2][nl] = b0.z; wsT[c0 +  3][nl] = b0.w;
      wsT[c0 +  4][nl] = b1.x; wsT[c0 +  5][nl] = b1.y; wsT[c0 +  6][nl] = b1.z; wsT[c0 +  7][nl] = b1.w;
      wsT[c0 +  8][nl] = b2.x; wsT[c0 +  9][nl] = b2.y; wsT[c0 + 10][nl] = b2.z; wsT[c0 + 11][nl] = b2.w;
      wsT[c0 + 12][nl] = b3.x; wsT[c0 + 13][nl] = b3.y; wsT[c0 + 14][nl] = b3.z; wsT[c0 + 15][nl] = b3.w;
    }
    __syncthreads();

    float acc[4][4];
    #pragma unroll
    for (int i = 0; i < 4; i++)
      #pragma unroll
      for (int j = 0; j < 4; j++) acc[i][j] = 0.f;

    #pragma unroll 8
    for (int kk = 0; kk < 64; kk++) {
      float4 a = *(const float4*)&xsT[kk][tx * 4];
      float4 b = *(const float4*)&wsT[kk][ty * 4];
      acc[0][0] += a.x * b.x; acc[0][1] += a.x * b.y; acc[0][2] += a.x * b.z; acc[0][3] += a.x * b.w;
      acc[1][0] += a.y * b.x; acc[1][1] += a.y * b.y; acc[1][2] += a.y * b.z; acc[1][3] += a.y * b.w;
      acc[2][0] += a.z * b.x; acc[2][1] += a.z * b.y; acc[2][2] += a.z * b.z; acc[2][3] += a.z * b.w;
      acc[3][0] += a.w * b.x; acc[3][1] += a.w * b.y; acc[3][2] += a.w * b.z; acc[3][3] += a.w * b.w;
    }

    const int n0 = tileN + tx * 4;
    const int col0 = rowbase + ty * 4;   // 4-aligned global channel
    const float4 bb = *(const float4*)(bias + col0);
    #pragma unroll
    for (int i = 0; i < 4; i++) {
      const int n = n0 + i;
      if (n >= NN) continue;
      const float r0 = acc[i][0] + bb.x, r1 = acc[i][1] + bb.y;
      const float r2 = acc[i][2] + bb.z, r3 = acc[i][3] + bb.w;
      if (jt < 2) {
        *(float4*)(qs + (size_t)n * 128 + col0) = make_float4(r0, r1, r2, r3);
      } else if (jt < 6) {
        const int entry = col0 >> 2;             // 0..31
        unsigned pk = 0;
        pk = __builtin_amdgcn_cvt_pk_fp8_f32(r0, r1, pk, false);
        pk = __builtin_amdgcn_cvt_pk_fp8_f32(r2, r3, pk, true);
        kvp[(size_t)n * 64 + entry * 2 + ((jt >= 4) ? 1 : 0)] = pk;
      } else {
        *(float4*)(skip + (size_t)n * 64 + col0) = make_float4(r0, r1, r2, r3);
      }
    }
  }
}

// ---------------- S2a: per-block partial sums (49 blocks x 1024) ------------
__global__ __launch_bounds__(1024) void k_scanA(const int* __restrict__ cnt, int* __restrict__ bsum) {
  __shared__ int wsum[16];
  const int t = threadIdx.x, lane = t & 63, wid = t >> 6;
  const int i = blockIdx.x * 1024 + t;
  int val = (i < NN) ? cnt[i] : 0;
  #pragma unroll
  for (int m = 1; m <= 32; m <<= 1) val += __shfl_xor(val, m);
  if (lane == 0) wsum[wid] = val;
  __syncthreads();
  if (t == 0) {
    int s = 0;
    #pragma unroll
    for (int j = 0; j < 16; j++) s += wsum[j];
    bsum[blockIdx.x] = s;
  }
}

// ---------------- S2c: local scan + (inline bsum prefix) -> rowptr ----------
__global__ __launch_bounds__(1024) void k_scanC(
    const int* __restrict__ cnt, const int* __restrict__ bsum, int* __restrict__ rowptr) {
  __shared__ int wsum[16];
  __shared__ int boff_s;
  const int t = threadIdx.x, lane = t & 63, wid = t >> 6;
  if (t < 64) {  // sum of bsum[0 .. blockIdx.x-1] with one wave
    int v = (t < blockIdx.x) ? bsum[t] : 0;
    #pragma unroll
    for (int m = 1; m <= 32; m <<= 1) v += __shfl_xor(v, m);
    if (t == 0) boff_s = v;
  }
  const int i = blockIdx.x * 1024 + t;
  const int val = (i < NN) ? cnt[i] : 0;
  int incl = val;
  #pragma unroll
  for (int off = 1; off < 64; off <<= 1) {
    int n = __shfl_up(incl, off, 64);
    if (lane >= off) incl += n;
  }
  if (lane == 63) wsum[wid] = incl;
  __syncthreads();
  if (t < 16) {
    int wv = wsum[t];
    int wincl = wv;
    #pragma unroll
    for (int off = 1; off < 16; off <<= 1) {
      int n = __shfl_up(wincl, off, 64);
      if (t >= off) wincl += n;
    }
    wsum[t] = wincl - wv;  // exclusive wave offsets
  }
  __syncthreads();
  if (i < NN) rowptr[i] = boff_s + wsum[wid] + incl - val;
  if (blockIdx.x == 0 && t == 0) rowptr[NN] = NE;
}

// ---------------- S3: bucket-fill edges sorted by dst (packed int2) ---------
// consumes cnt (atomicSub down to zero)
__global__ __launch_bounds__(256) void k_fill(
    const int* __restrict__ ei, const float* __restrict__ ea,
    const int* __restrict__ rowptr, int* __restrict__ cnt,
    int2* __restrict__ epack) {
  const int e = blockIdx.x * 256 + threadIdx.x;
  if (e < NE) {
    const int dst = ei[NE + e];
    const int p = atomicSub(&cnt[dst], 1) - 1;
    epack[rowptr[dst] + p] = make_int2(ei[e], __float_as_int(ea[e]));
  }
}

// ------- K2: per-dst softmax + agg, 2 edges per wave (half-wave each),
//         fp8 kv gather; then skip + LN0 + Wl + LN1 -------------------------
__global__ __launch_bounds__(256) void k_fused(
    const float* __restrict__ qs, const unsigned* __restrict__ kvp,
    const float* __restrict__ skip, const float* __restrict__ x,
    const int* __restrict__ rowptr, const int2* __restrict__ epack,
    const float* __restrict__ We,
    const float* __restrict__ Wl, const float* __restrict__ bl,
    const float* __restrict__ g0, const float* __restrict__ b0,
    const float* __restrict__ g1, const float* __restrict__ b1,
    float* __restrict__ out)
{
  __shared__ float wlT[64][65];
  __shared__ float scx[4][64];
  const int t = threadIdx.x;
  {
    const int jl = t >> 2, c0 = (t & 3) * 16;
    const float4* wr = (const float4*)(Wl + (size_t)jl * 64 + c0);
    float4 w0 = wr[0], w1 = wr[1], w2 = wr[2], w3 = wr[3];
    wlT[c0 +  0][jl] = w0.x; wlT[c0 +  1][jl] = w0.y; wlT[c0 +  2][jl] = w0.z; wlT[c0 +  3][jl] = w0.w;
    wlT[c0 +  4][jl] = w1.x; wlT[c0 +  5][jl] = w1.y; wlT[c0 +  6][jl] = w1.z; wlT[c0 +  7][jl] = w1.w;
    wlT[c0 +  8][jl] = w2.x; wlT[c0 +  9][jl] = w2.y; wlT[c0 + 10][jl] = w2.z; wlT[c0 + 11][jl] = w2.w;
    wlT[c0 + 12][jl] = w3.x; wlT[c0 + 13][jl] = w3.y; wlT[c0 + 14][jl] = w3.z; wlT[c0 + 15][jl] = w3.w;
  }

  const int w = t >> 6;
  const int dst = __builtin_amdgcn_readfirstlane(blockIdx.x * 4 + w);
  const int lane = t & 63;
  const int half = lane >> 5;      // which edge of the pair
  const int el = lane & 31;        // 4-channel group index (0..31 over 128 ch)

  const float4 qv = ((const float4*)(qs + (size_t)dst * 128))[el];
  const float4 we4 = ((const float4*)We)[el];

  // qwe per head: reduce over the 16-lane channel group
  float qwe = qv.x * we4.x + qv.y * we4.y + qv.z * we4.z + qv.w * we4.w;
  #pragma unroll
  for (int mm = 1; mm <= 8; mm <<= 1) qwe += __shfl_xor(qwe, mm);

  const int base = rowptr[dst];
  const int deg  = rowptr[dst + 1] - base;
  const uint2* kv8 = (const uint2*)kvp;
  const int2* ep = epack + base;

  float s = 0.f, sw = 0.f;
  float sv0 = 0.f, sv1 = 0.f, sv2 = 0.f, sv3 = 0.f;

#define PROC(u, wg, mask)                                                   \
  {                                                                         \
    const v2f k01 = __builtin_amdgcn_cvt_pk_f32_fp8((u).x, false);          \
    const v2f k23 = __builtin_amdgcn_cvt_pk_f32_fp8((u).x, true);           \
    const v2f v01 = __builtin_amdgcn_cvt_pk_f32_fp8((u).y, false);          \
    const v2f v23 = __builtin_amdgcn_cvt_pk_f32_fp8((u).y, true);           \
    float p = qv.x * k01.x + qv.y * k01.y + qv.z * k23.x + qv.w * k23.y;    \
    _Pragma("unroll")                                                       \
    for (int mm = 1; mm <= 8; mm <<= 1) p += __shfl_xor(p, mm);             \
    float e_ = __expf((p + (wg) * qwe) * 0.125f);                           \
    e_ = (mask) ? e_ : 0.f;                                                 \
    s += e_; sw += e_ * (wg);                                               \
    sv0 += e_ * v01.x; sv1 += e_ * v01.y;                                   \
    sv2 += e_ * v23.x; sv3 += e_ * v23.y;                                   \
  }

  int i = 0;
  for (; i + 4 <= deg; i += 4) {
    const int2 er0 = ep[i + half];
    const int2 er1 = ep[i + 2 + half];
    const uint2 u0 = kv8[(size_t)er0.x * 32 + el];
    const uint2 u1 = kv8[(size_t)er1.x * 32 + el];
    PROC(u0, __int_as_float(er0.y), true)
    PROC(u1, __int_as_float(er1.y), true)
  }
  for (; i < deg; i += 2) {
    const int idx = i + half;
    const bool valid = idx < deg;
    const int2 er = ep[valid ? idx : (deg - 1)];
    const uint2 u = kv8[(size_t)er.x * 32 + el];
    PROC(u, __int_as_float(er.y), valid)
  }
#undef PROC

  // combine the two half-wave partial accumulators
  s  += __shfl_xor(s, 32);
  sw += __shfl_xor(sw, 32);
  sv0 += __shfl_xor(sv0, 32); sv1 += __shfl_xor(sv1, 32);
  sv2 += __shfl_xor(sv2, 32); sv3 += __shfl_xor(sv3, 32);

  float a0 = 0.f, a1 = 0.f, a2 = 0.f, a3 = 0.f;
  if (deg > 0) {
    const float inv = 1.f / s;
    a0 = (sv0 + sw * we4.x) * inv;
    a1 = (sv1 + sw * we4.y) * inv;
    a2 = (sv2 + sw * we4.z) * inv;
    a3 = (sv3 + sw * we4.w) * inv;
  }
  // head mean: channel c of head0 (el<16) with channel c of head1 (el+16)
  a0 = 0.5f * (a0 + __shfl_xor(a0, 16));
  a1 = 0.5f * (a1 + __shfl_xor(a1, 16));
  a2 = 0.5f * (a2 + __shfl_xor(a2, 16));
  a3 = 0.5f * (a3 + __shfl_xor(a3, 16));
  if (half == 0 && el < 16) {
    ((float4*)scx[w])[el] = make_float4(a0, a1, a2, a3);
  }
  __syncthreads();

  const float hv = scx[w][lane] + skip[(size_t)dst * 64 + lane];

  // LN0 + residual
  float mean = wave_sum64(hv) * (1.f / 64.f);
  float dd = hv - mean;
  float var = wave_sum64(dd * dd) * (1.f / 64.f);
  const float x1 = x[(size_t)dst * 64 + lane] + dd * rsqrtf(var + 1e-5f) * g0[lane] + b0[lane];

  // y = x1 @ Wl^T + bl
  float y = bl[lane];
  #pragma unroll 16
  for (int kk = 0; kk < 64; kk++) {
    y += __shfl(x1, kk) * wlT[kk][lane];
  }
  // LN1 + residual
  float mean2 = wave_sum64(y) * (1.f / 64.f);
  float dy = y - mean2;
  float var2 = wave_sum64(dy * dy) * (1.f / 64.f);
  out[(size_t)dst * 64 + lane] = x1 + dy * rsqrtf(var2 + 1e-5f) * g1[lane] + b1[lane];
}

extern "C" void kernel_launch(void* const* d_in, const int* in_sizes, int n_in,
                              void* d_out, int out_size, void* d_ws, size_t ws_size,
                              hipStream_t stream) {
  const float* x     = (const float*)d_in[0];
  const int*   ei    = (const int*)d_in[1];
  const float* ea    = (const float*)d_in[2];
  const float* Wq    = (const float*)d_in[3];
  const float* bq    = (const float*)d_in[4];
  const float* Wk    = (const float*)d_in[5];
  const float* bk    = (const float*)d_in[6];
  const float* Wv    = (const float*)d_in[7];
  const float* bv    = (const float*)d_in[8];
  const float* We    = (const float*)d_in[9];
  const float* Wskip = (const float*)d_in[10];
  const float* bskip = (const float*)d_in[11];
  const float* Wl    = (const float*)d_in[12];
  const float* bl    = (const float*)d_in[13];
  const float* g0    = (const float*)d_in[14];
  const float* b0    = (const float*)d_in[15];
  const float* g1    = (const float*)d_in[16];
  const float* b1    = (const float*)d_in[17];
  float* out = (float*)d_out;

  float* ws = (float*)d_ws;
  size_t off = 0;
  float* qs   = ws + off; off += (size_t)NN * 128;
  unsigned* kvp = (unsigned*)(ws + off); off += (size_t)NN * 64;  // 256B/node fp8
  float* skip = ws + off; off += (size_t)NN * 64;
  int* cnt    = (int*)(ws + off); off += NN;
  int* rowptr = (int*)(ws + off); off += NN + 1;
  int* bsum   = (int*)(ws + off); off += 64;
  int2* epack = (int2*)(ws + off); off += (size_t)NE * 2;

  hipMemsetAsync(cnt, 0, (size_t)NN * sizeof(int), stream);

  dim3 gGemm((NN + 63) / 64, 2);  // y==1 -> histogram slice
  hipLaunchKernelGGL(k_gemm_qkv, gGemm, dim3(256), 0, stream,
                     x, Wq, bq, Wk, bk, Wv, bv, Wskip, bskip, ei, cnt, qs, kvp, skip);
  hipLaunchKernelGGL(k_scanA, dim3(49), dim3(1024), 0, stream, cnt, bsum);
  hipLaunchKernelGGL(k_scanC, dim3(49), dim3(1024), 0, stream, cnt, bsum, rowptr);
  hipLaunchKernelGGL(k_fill, dim3((NE + 255) / 256), dim3(256), 0, stream,
                     ei, ea, rowptr, cnt, epack);
  hipLaunchKernelGGL(k_fused, dim3(NN / 4), dim3(256), 0, stream,
                     qs, kvp, skip, x, rowptr, epack, We,
                     Wl, bl, g0, b0, g1, b1, out);
}

// Round 10
// 213.177 us; speedup vs baseline: 1.0951x; 1.0036x over previous
//
#include <hip/hip_runtime.h>
#include <hip/hip_fp16.h>

#define NN 50000
#define NE 800000

typedef unsigned short u16;
typedef float v2f __attribute__((ext_vector_type(2)));

__device__ __forceinline__ float wave_sum64(float p) {
  #pragma unroll
  for (int m = 1; m <= 32; m <<= 1) p += __shfl_xor(p, m);
  return p;
}

// ---- 16-lane all-reduce on the VALU pipe via DPP (no DS ops) ----
// groups are DPP rows (lanes 0-15,16-31,32-47,48-63), which matches our layout.
template <int CTRL>
__device__ __forceinline__ float dpp_add(float p) {
  const int v = __builtin_amdgcn_update_dpp(0, __float_as_int(p), CTRL, 0xF, 0xF, true);
  return p + __int_as_float(v);
}
__device__ __forceinline__ float red16(float p) {
  p = dpp_add<0xB1>(p);   // quad_perm [1,0,3,2]  : + lane^1
  p = dpp_add<0x4E>(p);   // quad_perm [2,3,0,1]  : + lane^2
  p = dpp_add<0x141>(p);  // row_half_mirror      : cross-quad within 8
  p = dpp_add<0x140>(p);  // row_mirror           : cross-8 within 16
  return p;
}

// ---------------- K1: fused QKV + skip GEMM (jt-loop) + (y==1) histogram ----
// q stored natural [n][128] fp32.
// kv stored [n][64] x u32 fp8-e4m3: entry e (4 channels): u32 k at idx 2e,
// u32 v at idx 2e+1. Global channel g = 4e spans head0 (0..63), head1 (64..127).
__global__ __launch_bounds__(256) void k_gemm_qkv(
    const float* __restrict__ x,
    const float* __restrict__ Wq, const float* __restrict__ bq,
    const float* __restrict__ Wk, const float* __restrict__ bk,
    const float* __restrict__ Wv, const float* __restrict__ bv,
    const float* __restrict__ Wskip, const float* __restrict__ bskip,
    const int* __restrict__ ei, int* __restrict__ cnt,
    float* __restrict__ qs, unsigned* __restrict__ kvp, float* __restrict__ skip)
{
  const int t = threadIdx.x;

  if (blockIdx.y == 1) {  // histogram slice
    const int e0 = blockIdx.x * 1024 + t;
    #pragma unroll
    for (int it = 0; it < 4; it++) {
      const int e = e0 + it * 256;
      if (e < NE) atomicAdd(&cnt[ei[NE + e]], 1);
    }
    return;
  }

  __shared__ float xsT[64][68];
  __shared__ float wsT[64][68];
  const int tileN = blockIdx.x * 64;

  {  // load x tile once
    const int nl = t >> 2, c0 = (t & 3) * 16;
    const int n = tileN + nl;
    float4 a0, a1, a2, a3;
    if (n < NN) {
      const float4* xr = (const float4*)(x + (size_t)n * 64 + c0);
      a0 = xr[0]; a1 = xr[1]; a2 = xr[2]; a3 = xr[3];
    } else {
      a0 = a1 = a2 = a3 = make_float4(0.f, 0.f, 0.f, 0.f);
    }
    xsT[c0 +  0][nl] = a0.x; xsT[c0 +  1][nl] = a0.y; xsT[c0 +  2][nl] = a0.z; xsT[c0 +  3][nl] = a0.w;
    xsT[c0 +  4][nl] = a1.x; xsT[c0 +  5][nl] = a1.y; xsT[c0 +  6][nl] = a1.z; xsT[c0 +  7][nl] = a1.w;
    xsT[c0 +  8][nl] = a2.x; xsT[c0 +  9][nl] = a2.y; xsT[c0 + 10][nl] = a2.z; xsT[c0 + 11][nl] = a2.w;
    xsT[c0 + 12][nl] = a3.x; xsT[c0 + 13][nl] = a3.y; xsT[c0 + 14][nl] = a3.z; xsT[c0 + 15][nl] = a3.w;
  }

  const int tx = t & 15, ty = t >> 4;

  for (int jt = 0; jt < 7; jt++) {
    const float* W; const float* bias; int rowbase;
    if (jt < 2)      { W = Wq;    bias = bq;    rowbase = jt * 64; }
    else if (jt < 4) { W = Wk;    bias = bk;    rowbase = (jt - 2) * 64; }
    else if (jt < 6) { W = Wv;    bias = bv;    rowbase = (jt - 4) * 64; }
    else             { W = Wskip; bias = bskip; rowbase = 0; }

    __syncthreads();  // previous MAC done (and xsT ready on first iter)
    {
      const int nl = t >> 2, c0 = (t & 3) * 16;
      const float4* wr = (const float4*)(W + (size_t)(rowbase + nl) * 64 + c0);
      float4 b0 = wr[0], b1 = wr[1], b2 = wr[2], b3 = wr[3];
      wsT[c0 +  0][nl] = b0.x; wsT[c0 +  1][nl] = b0.y; wsT[c0 +  2][nl] = b0.z; wsT[c0 +  3][nl] = b0.w;
      wsT[c0 +  4][nl] = b1.x; wsT[c0 +  5][nl] = b1.y; wsT[c0 +  6][nl] = b1.z; wsT[c0 +  7][nl] = b1.w;
      wsT[c0 +  8][nl] = b2.x; wsT[c0 +  9][nl] = b2.y; wsT[c0 + 10][nl] = b2.z; wsT[c0 + 11][nl] = b2.w;
      wsT[c0 + 12][nl] = b3.x; wsT[c0 + 13][nl] = b3.y; wsT[c0 + 14][nl] = b3.z; wsT[c0 + 15][nl] = b3.w;
    }
    __syncthreads();

    float acc[4][4];
    #pragma unroll
    for (int i = 0; i < 4; i++)
      #pragma unroll
      for (int j = 0; j < 4; j++) acc[i][j] = 0.f;

    #pragma unroll 8
    for (int kk = 0; kk < 64; kk++) {
      float4 a = *(const float4*)&xsT[kk][tx * 4];
      float4 b = *(const float4*)&wsT[kk][ty * 4];
      acc[0][0] += a.x * b.x; acc[0][1] += a.x * b.y; acc[0][2] += a.x * b.z; acc[0][3] += a.x * b.w;
      acc[1][0] += a.y * b.x; acc[1][1] += a.y * b.y; acc[1][2] += a.y * b.z; acc[1][3] += a.y * b.w;
      acc[2][0] += a.z * b.x; acc[2][1] += a.z * b.y; acc[2][2] += a.z * b.z; acc[2][3] += a.z * b.w;
      acc[3][0] += a.w * b.x; acc[3][1] += a.w * b.y; acc[3][2] += a.w * b.z; acc[3][3] += a.w * b.w;
    }

    const int n0 = tileN + tx * 4;
    const int col0 = rowbase + ty * 4;   // 4-aligned global channel
    const float4 bb = *(const float4*)(bias + col0);
    #pragma unroll
    for (int i = 0; i < 4; i++) {
      const int n = n0 + i;
      if (n >= NN) continue;
      const float r0 = acc[i][0] + bb.x, r1 = acc[i][1] + bb.y;
      const float r2 = acc[i][2] + bb.z, r3 = acc[i][3] + bb.w;
      if (jt < 2) {
        *(float4*)(qs + (size_t)n * 128 + col0) = make_float4(r0, r1, r2, r3);
      } else if (jt < 6) {
        const int entry = col0 >> 2;             // 0..31
        unsigned pk = 0;
        pk = __builtin_amdgcn_cvt_pk_fp8_f32(r0, r1, pk, false);
        pk = __builtin_amdgcn_cvt_pk_fp8_f32(r2, r3, pk, true);
        kvp[(size_t)n * 64 + entry * 2 + ((jt >= 4) ? 1 : 0)] = pk;
      } else {
        *(float4*)(skip + (size_t)n * 64 + col0) = make_float4(r0, r1, r2, r3);
      }
    }
  }
}

// ---------------- S2a: per-block partial sums (49 blocks x 1024) ------------
__global__ __launch_bounds__(1024) void k_scanA(const int* __restrict__ cnt, int* __restrict__ bsum) {
  __shared__ int wsum[16];
  const int t = threadIdx.x, lane = t & 63, wid = t >> 6;
  const int i = blockIdx.x * 1024 + t;
  int val = (i < NN) ? cnt[i] : 0;
  #pragma unroll
  for (int m = 1; m <= 32; m <<= 1) val += __shfl_xor(val, m);
  if (lane == 0) wsum[wid] = val;
  __syncthreads();
  if (t == 0) {
    int s = 0;
    #pragma unroll
    for (int j = 0; j < 16; j++) s += wsum[j];
    bsum[blockIdx.x] = s;
  }
}

// ---------------- S2c: local scan + (inline bsum prefix) -> rowptr ----------
__global__ __launch_bounds__(1024) void k_scanC(
    const int* __restrict__ cnt, const int* __restrict__ bsum, int* __restrict__ rowptr) {
  __shared__ int wsum[16];
  __shared__ int boff_s;
  const int t = threadIdx.x, lane = t & 63, wid = t >> 6;
  if (t < 64) {  // sum of bsum[0 .. blockIdx.x-1] with one wave
    int v = (t < blockIdx.x) ? bsum[t] : 0;
    #pragma unroll
    for (int m = 1; m <= 32; m <<= 1) v += __shfl_xor(v, m);
    if (t == 0) boff_s = v;
  }
  const int i = blockIdx.x * 1024 + t;
  const int val = (i < NN) ? cnt[i] : 0;
  int incl = val;
  #pragma unroll
  for (int off = 1; off < 64; off <<= 1) {
    int n = __shfl_up(incl, off, 64);
    if (lane >= off) incl += n;
  }
  if (lane == 63) wsum[wid] = incl;
  __syncthreads();
  if (t < 16) {
    int wv = wsum[t];
    int wincl = wv;
    #pragma unroll
    for (int off = 1; off < 16; off <<= 1) {
      int n = __shfl_up(wincl, off, 64);
      if (t >= off) wincl += n;
    }
    wsum[t] = wincl - wv;  // exclusive wave offsets
  }
  __syncthreads();
  if (i < NN) rowptr[i] = boff_s + wsum[wid] + incl - val;
  if (blockIdx.x == 0 && t == 0) rowptr[NN] = NE;
}

// ---------------- S3: bucket-fill edges sorted by dst (packed int2) ---------
// consumes cnt (atomicSub down to zero)
__global__ __launch_bounds__(256) void k_fill(
    const int* __restrict__ ei, const float* __restrict__ ea,
    const int* __restrict__ rowptr, int* __restrict__ cnt,
    int2* __restrict__ epack) {
  const int e = blockIdx.x * 256 + threadIdx.x;
  if (e < NE) {
    const int dst = ei[NE + e];
    const int p = atomicSub(&cnt[dst], 1) - 1;
    epack[rowptr[dst] + p] = make_int2(ei[e], __float_as_int(ea[e]));
  }
}

// ------- K2: per-dst softmax + agg, 2 edges per wave (half-wave each),
//         fp8 kv gather, DPP reduce; then skip + LN0 + Wl + LN1 -------------
__global__ __launch_bounds__(256) void k_fused(
    const float* __restrict__ qs, const unsigned* __restrict__ kvp,
    const float* __restrict__ skip, const float* __restrict__ x,
    const int* __restrict__ rowptr, const int2* __restrict__ epack,
    const float* __restrict__ We,
    const float* __restrict__ Wl, const float* __restrict__ bl,
    const float* __restrict__ g0, const float* __restrict__ b0,
    const float* __restrict__ g1, const float* __restrict__ b1,
    float* __restrict__ out)
{
  __shared__ float wlT[64][65];
  __shared__ float scx[4][64];
  const int t = threadIdx.x;
  {
    const int jl = t >> 2, c0 = (t & 3) * 16;
    const float4* wr = (const float4*)(Wl + (size_t)jl * 64 + c0);
    float4 w0 = wr[0], w1 = wr[1], w2 = wr[2], w3 = wr[3];
    wlT[c0 +  0][jl] = w0.x; wlT[c0 +  1][jl] = w0.y; wlT[c0 +  2][jl] = w0.z; wlT[c0 +  3][jl] = w0.w;
    wlT[c0 +  4][jl] = w1.x; wlT[c0 +  5][jl] = w1.y; wlT[c0 +  6][jl] = w1.z; wlT[c0 +  7][jl] = w1.w;
    wlT[c0 +  8][jl] = w2.x; wlT[c0 +  9][jl] = w2.y; wlT[c0 + 10][jl] = w2.z; wlT[c0 + 11][jl] = w2.w;
    wlT[c0 + 12][jl] = w3.x; wlT[c0 + 13][jl] = w3.y; wlT[c0 + 14][jl] = w3.z; wlT[c0 + 15][jl] = w3.w;
  }

  const int w = t >> 6;
  const int dst = __builtin_amdgcn_readfirstlane(blockIdx.x * 4 + w);
  const int lane = t & 63;
  const int half = lane >> 5;      // which edge of the pair
  const int el = lane & 31;        // 4-channel group index (0..31 over 128 ch)

  const float4 qv = ((const float4*)(qs + (size_t)dst * 128))[el];
  const float4 we4 = ((const float4*)We)[el];
  // prefetch per-dst epilogue rows (hide under the edge loop)
  const float skipv = skip[(size_t)dst * 64 + lane];
  const float xv    = x[(size_t)dst * 64 + lane];

  // qwe per head: reduce over the 16-lane channel group (DPP)
  const float qwe = red16(qv.x * we4.x + qv.y * we4.y + qv.z * we4.z + qv.w * we4.w);

  const int base = rowptr[dst];
  const int deg  = rowptr[dst + 1] - base;
  const uint2* kv8 = (const uint2*)kvp;
  const int2* ep = epack + base;

  float s = 0.f, sw = 0.f;
  float sv0 = 0.f, sv1 = 0.f, sv2 = 0.f, sv3 = 0.f;

  // exp(z*0.125) == exp2(z * 0.125*log2(e))
  const float SCL = 0.18033688011112042f;

#define PROC(u, wg, mask)                                                   \
  {                                                                         \
    const v2f k01 = __builtin_amdgcn_cvt_pk_f32_fp8((u).x, false);          \
    const v2f k23 = __builtin_amdgcn_cvt_pk_f32_fp8((u).x, true);           \
    const v2f v01 = __builtin_amdgcn_cvt_pk_f32_fp8((u).y, false);          \
    const v2f v23 = __builtin_amdgcn_cvt_pk_f32_fp8((u).y, true);           \
    const float p = red16(qv.x * k01.x + qv.y * k01.y +                     \
                          qv.z * k23.x + qv.w * k23.y);                     \
    float e_ = exp2f((p + (wg) * qwe) * SCL);                               \
    e_ = (mask) ? e_ : 0.f;                                                 \
    s += e_; sw += e_ * (wg);                                               \
    sv0 += e_ * v01.x; sv1 += e_ * v01.y;                                   \
    sv2 += e_ * v23.x; sv3 += e_ * v23.y;                                   \
  }

  int i = 0;
  for (; i + 4 <= deg; i += 4) {
    const int2 er0 = ep[i + half];
    const int2 er1 = ep[i + 2 + half];
    const uint2 u0 = kv8[(size_t)er0.x * 32 + el];
    const uint2 u1 = kv8[(size_t)er1.x * 32 + el];
    PROC(u0, __int_as_float(er0.y), true)
    PROC(u1, __int_as_float(er1.y), true)
  }
  for (; i < deg; i += 2) {
    const int idx = i + half;
    const bool valid = idx < deg;
    const int2 er = ep[valid ? idx : (deg - 1)];
    const uint2 u = kv8[(size_t)er.x * 32 + el];
    PROC(u, __int_as_float(er.y), valid)
  }
#undef PROC

  // combine the two half-wave partial accumulators
  s  += __shfl_xor(s, 32);
  sw += __shfl_xor(sw, 32);
  sv0 += __shfl_xor(sv0, 32); sv1 += __shfl_xor(sv1, 32);
  sv2 += __shfl_xor(sv2, 32); sv3 += __shfl_xor(sv3, 32);

  float a0 = 0.f, a1 = 0.f, a2 = 0.f, a3 = 0.f;
  if (deg > 0) {
    const float inv = 1.f / s;
    a0 = (sv0 + sw * we4.x) * inv;
    a1 = (sv1 + sw * we4.y) * inv;
    a2 = (sv2 + sw * we4.z) * inv;
    a3 = (sv3 + sw * we4.w) * inv;
  }
  // head mean: channel c of head0 (el<16) with channel c of head1 (el+16)
  a0 = 0.5f * (a0 + __shfl_xor(a0, 16));
  a1 = 0.5f * (a1 + __shfl_xor(a1, 16));
  a2 = 0.5f * (a2 + __shfl_xor(a2, 16));
  a3 = 0.5f * (a3 + __shfl_xor(a3, 16));
  if (half == 0 && el < 16) {
    ((float4*)scx[w])[el] = make_float4(a0, a1, a2, a3);
  }
  __syncthreads();

  const float hv = scx[w][lane] + skipv;

  // LN0 + residual
  float mean = wave_sum64(hv) * (1.f / 64.f);
  float dd = hv - mean;
  float var = wave_sum64(dd * dd) * (1.f / 64.f);
  const float x1 = xv + dd * rsqrtf(var + 1e-5f) * g0[lane] + b0[lane];

  // y = x1 @ Wl^T + bl
  float y = bl[lane];
  #pragma unroll 16
  for (int kk = 0; kk < 64; kk++) {
    y += __shfl(x1, kk) * wlT[kk][lane];
  }
  // LN1 + residual
  float mean2 = wave_sum64(y) * (1.f / 64.f);
  float dy = y - mean2;
  float var2 = wave_sum64(dy * dy) * (1.f / 64.f);
  out[(size_t)dst * 64 + lane] = x1 + dy * rsqrtf(var2 + 1e-5f) * g1[lane] + b1[lane];
}

extern "C" void kernel_launch(void* const* d_in, const int* in_sizes, int n_in,
                              void* d_out, int out_size, void* d_ws, size_t ws_size,
                              hipStream_t stream) {
  const float* x     = (const float*)d_in[0];
  const int*   ei    = (const int*)d_in[1];
  const float* ea    = (const float*)d_in[2];
  const float* Wq    = (const float*)d_in[3];
  const float* bq    = (const float*)d_in[4];
  const float* Wk    = (const float*)d_in[5];
  const float* bk    = (const float*)d_in[6];
  const float* Wv    = (const float*)d_in[7];
  const float* bv    = (const float*)d_in[8];
  const float* We    = (const float*)d_in[9];
  const float* Wskip = (const float*)d_in[10];
  const float* bskip = (const float*)d_in[11];
  const float* Wl    = (const float*)d_in[12];
  const float* bl    = (const float*)d_in[13];
  const float* g0    = (const float*)d_in[14];
  const float* b0    = (const float*)d_in[15];
  const float* g1    = (const float*)d_in[16];
  const float* b1    = (const float*)d_in[17];
  float* out = (float*)d_out;

  float* ws = (float*)d_ws;
  size_t off = 0;
  float* qs   = ws + off; off += (size_t)NN * 128;
  unsigned* kvp = (unsigned*)(ws + off); off += (size_t)NN * 64;  // 256B/node fp8
  float* skip = ws + off; off += (size_t)NN * 64;
  int* cnt    = (int*)(ws + off); off += NN;
  int* rowptr = (int*)(ws + off); off += NN + 1;
  int* bsum   = (int*)(ws + off); off += 64;
  int2* epack = (int2*)(ws + off); off += (size_t)NE * 2;

  (void)hipMemsetAsync(cnt, 0, (size_t)NN * sizeof(int), stream);

  dim3 gGemm((NN + 63) / 64, 2);  // y==1 -> histogram slice
  hipLaunchKernelGGL(k_gemm_qkv, gGemm, dim3(256), 0, stream,
                     x, Wq, bq, Wk, bk, Wv, bv, Wskip, bskip, ei, cnt, qs, kvp, skip);
  hipLaunchKernelGGL(k_scanA, dim3(49), dim3(1024), 0, stream, cnt, bsum);
  hipLaunchKernelGGL(k_scanC, dim3(49), dim3(1024), 0, stream, cnt, bsum, rowptr);
  hipLaunchKernelGGL(k_fill, dim3((NE + 255) / 256), dim3(256), 0, stream,
                     ei, ea, rowptr, cnt, epack);
  hipLaunchKernelGGL(k_fused, dim3(NN / 4), dim3(256), 0, stream,
                     qs, kvp, skip, x, rowptr, epack, We,
                     Wl, bl, g0, b0, g1, b1, out);
}

// Round 11
// 207.354 us; speedup vs baseline: 1.1258x; 1.0281x over previous
//
#include <hip/hip_runtime.h>
#include <hip/hip_fp16.h>

#define NN 50000
#define NE 800000

typedef unsigned short u16;
typedef float v2f __attribute__((ext_vector_type(2)));

__device__ __forceinline__ float wave_sum64(float p) {
  #pragma unroll
  for (int m = 1; m <= 32; m <<= 1) p += __shfl_xor(p, m);
  return p;
}

// ---- 16-lane all-reduce on the VALU pipe via DPP (no DS ops) ----
// groups are DPP rows (lanes 0-15,16-31,32-47,48-63), which matches our layout.
template <int CTRL>
__device__ __forceinline__ float dpp_add(float p) {
  const int v = __builtin_amdgcn_update_dpp(0, __float_as_int(p), CTRL, 0xF, 0xF, true);
  return p + __int_as_float(v);
}
__device__ __forceinline__ float red16(float p) {
  p = dpp_add<0xB1>(p);   // quad_perm [1,0,3,2]  : + lane^1
  p = dpp_add<0x4E>(p);   // quad_perm [2,3,0,1]  : + lane^2
  p = dpp_add<0x141>(p);  // row_half_mirror      : cross-quad within 8
  p = dpp_add<0x140>(p);  // row_mirror           : cross-8 within 16
  return p;
}

// ---------------- K1: fused QKV + skip GEMM (jt-loop) + (y==1) histogram ----
// q stored natural [n][128] fp32.
// kv stored [n][64] x u32 fp8-e4m3: entry e (4 channels): u32 k at idx 2e,
// u32 v at idx 2e+1. Global channel g = 4e spans head0 (0..63), head1 (64..127).
__global__ __launch_bounds__(256) void k_gemm_qkv(
    const float* __restrict__ x,
    const float* __restrict__ Wq, const float* __restrict__ bq,
    const float* __restrict__ Wk, const float* __restrict__ bk,
    const float* __restrict__ Wv, const float* __restrict__ bv,
    const float* __restrict__ Wskip, const float* __restrict__ bskip,
    const int* __restrict__ ei, int* __restrict__ cnt,
    float* __restrict__ qs, unsigned* __restrict__ kvp, float* __restrict__ skip)
{
  const int t = threadIdx.x;

  if (blockIdx.y == 1) {  // histogram slice
    const int e0 = blockIdx.x * 1024 + t;
    #pragma unroll
    for (int it = 0; it < 4; it++) {
      const int e = e0 + it * 256;
      if (e < NE) atomicAdd(&cnt[ei[NE + e]], 1);
    }
    return;
  }

  __shared__ float xsT[64][68];
  __shared__ float wsT[64][68];
  const int tileN = blockIdx.x * 64;

  {  // load x tile once
    const int nl = t >> 2, c0 = (t & 3) * 16;
    const int n = tileN + nl;
    float4 a0, a1, a2, a3;
    if (n < NN) {
      const float4* xr = (const float4*)(x + (size_t)n * 64 + c0);
      a0 = xr[0]; a1 = xr[1]; a2 = xr[2]; a3 = xr[3];
    } else {
      a0 = a1 = a2 = a3 = make_float4(0.f, 0.f, 0.f, 0.f);
    }
    xsT[c0 +  0][nl] = a0.x; xsT[c0 +  1][nl] = a0.y; xsT[c0 +  2][nl] = a0.z; xsT[c0 +  3][nl] = a0.w;
    xsT[c0 +  4][nl] = a1.x; xsT[c0 +  5][nl] = a1.y; xsT[c0 +  6][nl] = a1.z; xsT[c0 +  7][nl] = a1.w;
    xsT[c0 +  8][nl] = a2.x; xsT[c0 +  9][nl] = a2.y; xsT[c0 + 10][nl] = a2.z; xsT[c0 + 11][nl] = a2.w;
    xsT[c0 + 12][nl] = a3.x; xsT[c0 + 13][nl] = a3.y; xsT[c0 + 14][nl] = a3.z; xsT[c0 + 15][nl] = a3.w;
  }

  const int tx = t & 15, ty = t >> 4;

  for (int jt = 0; jt < 7; jt++) {
    const float* W; const float* bias; int rowbase;
    if (jt < 2)      { W = Wq;    bias = bq;    rowbase = jt * 64; }
    else if (jt < 4) { W = Wk;    bias = bk;    rowbase = (jt - 2) * 64; }
    else if (jt < 6) { W = Wv;    bias = bv;    rowbase = (jt - 4) * 64; }
    else             { W = Wskip; bias = bskip; rowbase = 0; }

    __syncthreads();  // previous MAC done (and xsT ready on first iter)
    {
      const int nl = t >> 2, c0 = (t & 3) * 16;
      const float4* wr = (const float4*)(W + (size_t)(rowbase + nl) * 64 + c0);
      float4 b0 = wr[0], b1 = wr[1], b2 = wr[2], b3 = wr[3];
      wsT[c0 +  0][nl] = b0.x; wsT[c0 +  1][nl] = b0.y; wsT[c0 +  2][nl] = b0.z; wsT[c0 +  3][nl] = b0.w;
      wsT[c0 +  4][nl] = b1.x; wsT[c0 +  5][nl] = b1.y; wsT[c0 +  6][nl] = b1.z; wsT[c0 +  7][nl] = b1.w;
      wsT[c0 +  8][nl] = b2.x; wsT[c0 +  9][nl] = b2.y; wsT[c0 + 10][nl] = b2.z; wsT[c0 + 11][nl] = b2.w;
      wsT[c0 + 12][nl] = b3.x; wsT[c0 + 13][nl] = b3.y; wsT[c0 + 14][nl] = b3.z; wsT[c0 + 15][nl] = b3.w;
    }
    __syncthreads();

    float acc[4][4];
    #pragma unroll
    for (int i = 0; i < 4; i++)
      #pragma unroll
      for (int j = 0; j < 4; j++) acc[i][j] = 0.f;

    #pragma unroll 8
    for (int kk = 0; kk < 64; kk++) {
      float4 a = *(const float4*)&xsT[kk][tx * 4];
      float4 b = *(const float4*)&wsT[kk][ty * 4];
      acc[0][0] += a.x * b.x; acc[0][1] += a.x * b.y; acc[0][2] += a.x * b.z; acc[0][3] += a.x * b.w;
      acc[1][0] += a.y * b.x; acc[1][1] += a.y * b.y; acc[1][2] += a.y * b.z; acc[1][3] += a.y * b.w;
      acc[2][0] += a.z * b.x; acc[2][1] += a.z * b.y; acc[2][2] += a.z * b.z; acc[2][3] += a.z * b.w;
      acc[3][0] += a.w * b.x; acc[3][1] += a.w * b.y; acc[3][2] += a.w * b.z; acc[3][3] += a.w * b.w;
    }

    const int n0 = tileN + tx * 4;
    const int col0 = rowbase + ty * 4;   // 4-aligned global channel
    const float4 bb = *(const float4*)(bias + col0);
    #pragma unroll
    for (int i = 0; i < 4; i++) {
      const int n = n0 + i;
      if (n >= NN) continue;
      const float r0 = acc[i][0] + bb.x, r1 = acc[i][1] + bb.y;
      const float r2 = acc[i][2] + bb.z, r3 = acc[i][3] + bb.w;
      if (jt < 2) {
        *(float4*)(qs + (size_t)n * 128 + col0) = make_float4(r0, r1, r2, r3);
      } else if (jt < 6) {
        const int entry = col0 >> 2;             // 0..31
        unsigned pk = 0;
        pk = __builtin_amdgcn_cvt_pk_fp8_f32(r0, r1, pk, false);
        pk = __builtin_amdgcn_cvt_pk_fp8_f32(r2, r3, pk, true);
        kvp[(size_t)n * 64 + entry * 2 + ((jt >= 4) ? 1 : 0)] = pk;
      } else {
        *(float4*)(skip + (size_t)n * 64 + col0) = make_float4(r0, r1, r2, r3);
      }
    }
  }
}

// ---------------- S2a: per-block partial sums (49 blocks x 1024) ------------
__global__ __launch_bounds__(1024) void k_scanA(const int* __restrict__ cnt, int* __restrict__ bsum) {
  __shared__ int wsum[16];
  const int t = threadIdx.x, lane = t & 63, wid = t >> 6;
  const int i = blockIdx.x * 1024 + t;
  int val = (i < NN) ? cnt[i] : 0;
  #pragma unroll
  for (int m = 1; m <= 32; m <<= 1) val += __shfl_xor(val, m);
  if (lane == 0) wsum[wid] = val;
  __syncthreads();
  if (t == 0) {
    int s = 0;
    #pragma unroll
    for (int j = 0; j < 16; j++) s += wsum[j];
    bsum[blockIdx.x] = s;
  }
}

// ---------------- S2c: local scan + (inline bsum prefix) -> rowptr ----------
__global__ __launch_bounds__(1024) void k_scanC(
    const int* __restrict__ cnt, const int* __restrict__ bsum, int* __restrict__ rowptr) {
  __shared__ int wsum[16];
  __shared__ int boff_s;
  const int t = threadIdx.x, lane = t & 63, wid = t >> 6;
  if (t < 64) {  // sum of bsum[0 .. blockIdx.x-1] with one wave
    int v = (t < blockIdx.x) ? bsum[t] : 0;
    #pragma unroll
    for (int m = 1; m <= 32; m <<= 1) v += __shfl_xor(v, m);
    if (t == 0) boff_s = v;
  }
  const int i = blockIdx.x * 1024 + t;
  const int val = (i < NN) ? cnt[i] : 0;
  int incl = val;
  #pragma unroll
  for (int off = 1; off < 64; off <<= 1) {
    int n = __shfl_up(incl, off, 64);
    if (lane >= off) incl += n;
  }
  if (lane == 63) wsum[wid] = incl;
  __syncthreads();
  if (t < 16) {
    int wv = wsum[t];
    int wincl = wv;
    #pragma unroll
    for (int off = 1; off < 16; off <<= 1) {
      int n = __shfl_up(wincl, off, 64);
      if (t >= off) wincl += n;
    }
    wsum[t] = wincl - wv;  // exclusive wave offsets
  }
  __syncthreads();
  if (i < NN) rowptr[i] = boff_s + wsum[wid] + incl - val;
  if (blockIdx.x == 0 && t == 0) rowptr[NN] = NE;
}

// ---------------- S3: bucket-fill edges sorted by dst (packed int2) ---------
// consumes cnt (atomicSub down to zero)
__global__ __launch_bounds__(256) void k_fill(
    const int* __restrict__ ei, const float* __restrict__ ea,
    const int* __restrict__ rowptr, int* __restrict__ cnt,
    int2* __restrict__ epack) {
  const int e = blockIdx.x * 256 + threadIdx.x;
  if (e < NE) {
    const int dst = ei[NE + e];
    const int p = atomicSub(&cnt[dst], 1) - 1;
    epack[rowptr[dst] + p] = make_int2(ei[e], __float_as_int(ea[e]));
  }
}

// ------- K2: per-dst softmax + agg, 2 edges per wave (half-wave each),
//         fp8 kv gather, DPP reduce, 8-edge unroll (4 loads in flight) ------
__global__ __launch_bounds__(256) void k_fused(
    const float* __restrict__ qs, const unsigned* __restrict__ kvp,
    const float* __restrict__ skip, const float* __restrict__ x,
    const int* __restrict__ rowptr, const int2* __restrict__ epack,
    const float* __restrict__ We,
    const float* __restrict__ Wl, const float* __restrict__ bl,
    const float* __restrict__ g0, const float* __restrict__ b0,
    const float* __restrict__ g1, const float* __restrict__ b1,
    float* __restrict__ out)
{
  __shared__ float wlT[64][65];
  __shared__ float scx[4][64];
  const int t = threadIdx.x;
  {
    const int jl = t >> 2, c0 = (t & 3) * 16;
    const float4* wr = (const float4*)(Wl + (size_t)jl * 64 + c0);
    float4 w0 = wr[0], w1 = wr[1], w2 = wr[2], w3 = wr[3];
    wlT[c0 +  0][jl] = w0.x; wlT[c0 +  1][jl] = w0.y; wlT[c0 +  2][jl] = w0.z; wlT[c0 +  3][jl] = w0.w;
    wlT[c0 +  4][jl] = w1.x; wlT[c0 +  5][jl] = w1.y; wlT[c0 +  6][jl] = w1.z; wlT[c0 +  7][jl] = w1.w;
    wlT[c0 +  8][jl] = w2.x; wlT[c0 +  9][jl] = w2.y; wlT[c0 + 10][jl] = w2.z; wlT[c0 + 11][jl] = w2.w;
    wlT[c0 + 12][jl] = w3.x; wlT[c0 + 13][jl] = w3.y; wlT[c0 + 14][jl] = w3.z; wlT[c0 + 15][jl] = w3.w;
  }

  const int w = t >> 6;
  const int dst = __builtin_amdgcn_readfirstlane(blockIdx.x * 4 + w);
  const int lane = t & 63;
  const int half = lane >> 5;      // which edge of the pair
  const int el = lane & 31;        // 4-channel group index (0..31 over 128 ch)

  const float4 qv = ((const float4*)(qs + (size_t)dst * 128))[el];
  const float4 we4 = ((const float4*)We)[el];
  // prefetch per-dst epilogue rows (hide under the edge loop)
  const float skipv = skip[(size_t)dst * 64 + lane];
  const float xv    = x[(size_t)dst * 64 + lane];

  // qwe per head: reduce over the 16-lane channel group (DPP)
  const float qwe = red16(qv.x * we4.x + qv.y * we4.y + qv.z * we4.z + qv.w * we4.w);

  const int base = rowptr[dst];
  const int deg  = rowptr[dst + 1] - base;
  const uint2* kv8 = (const uint2*)kvp;
  const int2* ep = epack + base;

  float s = 0.f, sw = 0.f;
  float sv0 = 0.f, sv1 = 0.f, sv2 = 0.f, sv3 = 0.f;

  // exp(z*0.125) == exp2(z * 0.125*log2(e))
  const float SCL = 0.18033688011112042f;

#define PROC(u, wg, mask)                                                   \
  {                                                                         \
    const v2f k01 = __builtin_amdgcn_cvt_pk_f32_fp8((u).x, false);          \
    const v2f k23 = __builtin_amdgcn_cvt_pk_f32_fp8((u).x, true);           \
    const v2f v01 = __builtin_amdgcn_cvt_pk_f32_fp8((u).y, false);          \
    const v2f v23 = __builtin_amdgcn_cvt_pk_f32_fp8((u).y, true);           \
    const float p = red16(qv.x * k01.x + qv.y * k01.y +                     \
                          qv.z * k23.x + qv.w * k23.y);                     \
    float e_ = exp2f((p + (wg) * qwe) * SCL);                               \
    e_ = (mask) ? e_ : 0.f;                                                 \
    s += e_; sw += e_ * (wg);                                               \
    sv0 += e_ * v01.x; sv1 += e_ * v01.y;                                   \
    sv2 += e_ * v23.x; sv3 += e_ * v23.y;                                   \
  }

  int i = 0;
  // 8-edge unroll: 4 independent kv gathers issued before any consumption
  for (; i + 8 <= deg; i += 8) {
    const int2 er0 = ep[i + half];
    const int2 er1 = ep[i + 2 + half];
    const int2 er2 = ep[i + 4 + half];
    const int2 er3 = ep[i + 6 + half];
    const uint2 u0 = kv8[(size_t)er0.x * 32 + el];
    const uint2 u1 = kv8[(size_t)er1.x * 32 + el];
    const uint2 u2 = kv8[(size_t)er2.x * 32 + el];
    const uint2 u3 = kv8[(size_t)er3.x * 32 + el];
    PROC(u0, __int_as_float(er0.y), true)
    PROC(u1, __int_as_float(er1.y), true)
    PROC(u2, __int_as_float(er2.y), true)
    PROC(u3, __int_as_float(er3.y), true)
  }
  for (; i + 4 <= deg; i += 4) {
    const int2 er0 = ep[i + half];
    const int2 er1 = ep[i + 2 + half];
    const uint2 u0 = kv8[(size_t)er0.x * 32 + el];
    const uint2 u1 = kv8[(size_t)er1.x * 32 + el];
    PROC(u0, __int_as_float(er0.y), true)
    PROC(u1, __int_as_float(er1.y), true)
  }
  for (; i < deg; i += 2) {
    const int idx = i + half;
    const bool valid = idx < deg;
    const int2 er = ep[valid ? idx : (deg - 1)];
    const uint2 u = kv8[(size_t)er.x * 32 + el];
    PROC(u, __int_as_float(er.y), valid)
  }
#undef PROC

  // combine the two half-wave partial accumulators
  s  += __shfl_xor(s, 32);
  sw += __shfl_xor(sw, 32);
  sv0 += __shfl_xor(sv0, 32); sv1 += __shfl_xor(sv1, 32);
  sv2 += __shfl_xor(sv2, 32); sv3 += __shfl_xor(sv3, 32);

  float a0 = 0.f, a1 = 0.f, a2 = 0.f, a3 = 0.f;
  if (deg > 0) {
    const float inv = 1.f / s;
    a0 = (sv0 + sw * we4.x) * inv;
    a1 = (sv1 + sw * we4.y) * inv;
    a2 = (sv2 + sw * we4.z) * inv;
    a3 = (sv3 + sw * we4.w) * inv;
  }
  // head mean: channel c of head0 (el<16) with channel c of head1 (el+16)
  a0 = 0.5f * (a0 + __shfl_xor(a0, 16));
  a1 = 0.5f * (a1 + __shfl_xor(a1, 16));
  a2 = 0.5f * (a2 + __shfl_xor(a2, 16));
  a3 = 0.5f * (a3 + __shfl_xor(a3, 16));
  if (half == 0 && el < 16) {
    ((float4*)scx[w])[el] = make_float4(a0, a1, a2, a3);
  }
  __syncthreads();

  const float hv = scx[w][lane] + skipv;

  // LN0 + residual
  float mean = wave_sum64(hv) * (1.f / 64.f);
  float dd = hv - mean;
  float var = wave_sum64(dd * dd) * (1.f / 64.f);
  const float x1 = xv + dd * rsqrtf(var + 1e-5f) * g0[lane] + b0[lane];

  // y = x1 @ Wl^T + bl
  float y = bl[lane];
  #pragma unroll 16
  for (int kk = 0; kk < 64; kk++) {
    y += __shfl(x1, kk) * wlT[kk][lane];
  }
  // LN1 + residual
  float mean2 = wave_sum64(y) * (1.f / 64.f);
  float dy = y - mean2;
  float var2 = wave_sum64(dy * dy) * (1.f / 64.f);
  out[(size_t)dst * 64 + lane] = x1 + dy * rsqrtf(var2 + 1e-5f) * g1[lane] + b1[lane];
}

extern "C" void kernel_launch(void* const* d_in, const int* in_sizes, int n_in,
                              void* d_out, int out_size, void* d_ws, size_t ws_size,
                              hipStream_t stream) {
  const float* x     = (const float*)d_in[0];
  const int*   ei    = (const int*)d_in[1];
  const float* ea    = (const float*)d_in[2];
  const float* Wq    = (const float*)d_in[3];
  const float* bq    = (const float*)d_in[4];
  const float* Wk    = (const float*)d_in[5];
  const float* bk    = (const float*)d_in[6];
  const float* Wv    = (const float*)d_in[7];
  const float* bv    = (const float*)d_in[8];
  const float* We    = (const float*)d_in[9];
  const float* Wskip = (const float*)d_in[10];
  const float* bskip = (const float*)d_in[11];
  const float* Wl    = (const float*)d_in[12];
  const float* bl    = (const float*)d_in[13];
  const float* g0    = (const float*)d_in[14];
  const float* b0    = (const float*)d_in[15];
  const float* g1    = (const float*)d_in[16];
  const float* b1    = (const float*)d_in[17];
  float* out = (float*)d_out;

  float* ws = (float*)d_ws;
  size_t off = 0;
  float* qs   = ws + off; off += (size_t)NN * 128;
  unsigned* kvp = (unsigned*)(ws + off); off += (size_t)NN * 64;  // 256B/node fp8
  float* skip = ws + off; off += (size_t)NN * 64;
  int* cnt    = (int*)(ws + off); off += NN;
  int* rowptr = (int*)(ws + off); off += NN + 1;
  int* bsum   = (int*)(ws + off); off += 64;
  int2* epack = (int2*)(ws + off); off += (size_t)NE * 2;

  (void)hipMemsetAsync(cnt, 0, (size_t)NN * sizeof(int), stream);

  dim3 gGemm((NN + 63) / 64, 2);  // y==1 -> histogram slice
  hipLaunchKernelGGL(k_gemm_qkv, gGemm, dim3(256), 0, stream,
                     x, Wq, bq, Wk, bk, Wv, bv, Wskip, bskip, ei, cnt, qs, kvp, skip);
  hipLaunchKernelGGL(k_scanA, dim3(49), dim3(1024), 0, stream, cnt, bsum);
  hipLaunchKernelGGL(k_scanC, dim3(49), dim3(1024), 0, stream, cnt, bsum, rowptr);
  hipLaunchKernelGGL(k_fill, dim3((NE + 255) / 256), dim3(256), 0, stream,
                     ei, ea, rowptr, cnt, epack);
  hipLaunchKernelGGL(k_fused, dim3(NN / 4), dim3(256), 0, stream,
                     qs, kvp, skip, x, rowptr, epack, We,
                     Wl, bl, g0, b0, g1, b1, out);
}

// Round 12
// 183.129 us; speedup vs baseline: 1.2748x; 1.1323x over previous
//
#include <hip/hip_runtime.h>
#include <hip/hip_fp16.h>

#define NN 50000
#define NE 800000

typedef unsigned short u16;
typedef float v2f __attribute__((ext_vector_type(2)));

// ---- 16-lane all-reduce on the VALU pipe via DPP (no DS ops) ----
template <int CTRL>
__device__ __forceinline__ float dpp_add(float p) {
  const int v = __builtin_amdgcn_update_dpp(0, __float_as_int(p), CTRL, 0xF, 0xF, true);
  return p + __int_as_float(v);
}
__device__ __forceinline__ float red16(float p) {
  p = dpp_add<0xB1>(p);   // quad_perm [1,0,3,2]
  p = dpp_add<0x4E>(p);   // quad_perm [2,3,0,1]
  p = dpp_add<0x141>(p);  // row_half_mirror
  p = dpp_add<0x140>(p);  // row_mirror
  return p;
}

// ---------------- K1: fused QKV + skip GEMM (jt-loop) + (y==1) histogram ----
__global__ __launch_bounds__(256) void k_gemm_qkv(
    const float* __restrict__ x,
    const float* __restrict__ Wq, const float* __restrict__ bq,
    const float* __restrict__ Wk, const float* __restrict__ bk,
    const float* __restrict__ Wv, const float* __restrict__ bv,
    const float* __restrict__ Wskip, const float* __restrict__ bskip,
    const int* __restrict__ ei, int* __restrict__ cnt,
    float* __restrict__ qs, unsigned* __restrict__ kvp, float* __restrict__ skip)
{
  const int t = threadIdx.x;

  if (blockIdx.y == 1) {  // histogram slice
    const int e0 = blockIdx.x * 1024 + t;
    #pragma unroll
    for (int it = 0; it < 4; it++) {
      const int e = e0 + it * 256;
      if (e < NE) atomicAdd(&cnt[ei[NE + e]], 1);
    }
    return;
  }

  __shared__ float xsT[64][68];
  __shared__ float wsT[64][68];
  const int tileN = blockIdx.x * 64;

  {  // load x tile once
    const int nl = t >> 2, c0 = (t & 3) * 16;
    const int n = tileN + nl;
    float4 a0, a1, a2, a3;
    if (n < NN) {
      const float4* xr = (const float4*)(x + (size_t)n * 64 + c0);
      a0 = xr[0]; a1 = xr[1]; a2 = xr[2]; a3 = xr[3];
    } else {
      a0 = a1 = a2 = a3 = make_float4(0.f, 0.f, 0.f, 0.f);
    }
    xsT[c0 +  0][nl] = a0.x; xsT[c0 +  1][nl] = a0.y; xsT[c0 +  2][nl] = a0.z; xsT[c0 +  3][nl] = a0.w;
    xsT[c0 +  4][nl] = a1.x; xsT[c0 +  5][nl] = a1.y; xsT[c0 +  6][nl] = a1.z; xsT[c0 +  7][nl] = a1.w;
    xsT[c0 +  8][nl] = a2.x; xsT[c0 +  9][nl] = a2.y; xsT[c0 + 10][nl] = a2.z; xsT[c0 + 11][nl] = a2.w;
    xsT[c0 + 12][nl] = a3.x; xsT[c0 + 13][nl] = a3.y; xsT[c0 + 14][nl] = a3.z; xsT[c0 + 15][nl] = a3.w;
  }

  const int tx = t & 15, ty = t >> 4;

  for (int jt = 0; jt < 7; jt++) {
    const float* W; const float* bias; int rowbase;
    if (jt < 2)      { W = Wq;    bias = bq;    rowbase = jt * 64; }
    else if (jt < 4) { W = Wk;    bias = bk;    rowbase = (jt - 2) * 64; }
    else if (jt < 6) { W = Wv;    bias = bv;    rowbase = (jt - 4) * 64; }
    else             { W = Wskip; bias = bskip; rowbase = 0; }

    __syncthreads();
    {
      const int nl = t >> 2, c0 = (t & 3) * 16;
      const float4* wr = (const float4*)(W + (size_t)(rowbase + nl) * 64 + c0);
      float4 b0 = wr[0], b1 = wr[1], b2 = wr[2], b3 = wr[3];
      wsT[c0 +  0][nl] = b0.x; wsT[c0 +  1][nl] = b0.y; wsT[c0 +  2][nl] = b0.z; wsT[c0 +  3][nl] = b0.w;
      wsT[c0 +  4][nl] = b1.x; wsT[c0 +  5][nl] = b1.y; wsT[c0 +  6][nl] = b1.z; wsT[c0 +  7][nl] = b1.w;
      wsT[c0 +  8][nl] = b2.x; wsT[c0 +  9][nl] = b2.y; wsT[c0 + 10][nl] = b2.z; wsT[c0 + 11][nl] = b2.w;
      wsT[c0 + 12][nl] = b3.x; wsT[c0 + 13][nl] = b3.y; wsT[c0 + 14][nl] = b3.z; wsT[c0 + 15][nl] = b3.w;
    }
    __syncthreads();

    float acc[4][4];
    #pragma unroll
    for (int i = 0; i < 4; i++)
      #pragma unroll
      for (int j = 0; j < 4; j++) acc[i][j] = 0.f;

    #pragma unroll 8
    for (int kk = 0; kk < 64; kk++) {
      float4 a = *(const float4*)&xsT[kk][tx * 4];
      float4 b = *(const float4*)&wsT[kk][ty * 4];
      acc[0][0] += a.x * b.x; acc[0][1] += a.x * b.y; acc[0][2] += a.x * b.z; acc[0][3] += a.x * b.w;
      acc[1][0] += a.y * b.x; acc[1][1] += a.y * b.y; acc[1][2] += a.y * b.z; acc[1][3] += a.y * b.w;
      acc[2][0] += a.z * b.x; acc[2][1] += a.z * b.y; acc[2][2] += a.z * b.z; acc[2][3] += a.z * b.w;
      acc[3][0] += a.w * b.x; acc[3][1] += a.w * b.y; acc[3][2] += a.w * b.z; acc[3][3] += a.w * b.w;
    }

    const int n0 = tileN + tx * 4;
    const int col0 = rowbase + ty * 4;
    const float4 bb = *(const float4*)(bias + col0);
    #pragma unroll
    for (int i = 0; i < 4; i++) {
      const int n = n0 + i;
      if (n >= NN) continue;
      const float r0 = acc[i][0] + bb.x, r1 = acc[i][1] + bb.y;
      const float r2 = acc[i][2] + bb.z, r3 = acc[i][3] + bb.w;
      if (jt < 2) {
        *(float4*)(qs + (size_t)n * 128 + col0) = make_float4(r0, r1, r2, r3);
      } else if (jt < 6) {
        const int entry = col0 >> 2;
        unsigned pk = 0;
        pk = __builtin_amdgcn_cvt_pk_fp8_f32(r0, r1, pk, false);
        pk = __builtin_amdgcn_cvt_pk_fp8_f32(r2, r3, pk, true);
        kvp[(size_t)n * 64 + entry * 2 + ((jt >= 4) ? 1 : 0)] = pk;
      } else {
        *(float4*)(skip + (size_t)n * 64 + col0) = make_float4(r0, r1, r2, r3);
      }
    }
  }
}

// ---------------- S2a: per-block partial sums (49 blocks x 1024) ------------
__global__ __launch_bounds__(1024) void k_scanA(const int* __restrict__ cnt, int* __restrict__ bsum) {
  __shared__ int wsum[16];
  const int t = threadIdx.x, lane = t & 63, wid = t >> 6;
  const int i = blockIdx.x * 1024 + t;
  int val = (i < NN) ? cnt[i] : 0;
  #pragma unroll
  for (int m = 1; m <= 32; m <<= 1) val += __shfl_xor(val, m);
  if (lane == 0) wsum[wid] = val;
  __syncthreads();
  if (t == 0) {
    int s = 0;
    #pragma unroll
    for (int j = 0; j < 16; j++) s += wsum[j];
    bsum[blockIdx.x] = s;
  }
}

// ---------------- S2c: local scan + inline bsum prefix -> rowptr;
//                  also overwrite cnt[i] with inclusive scan (= rowptr[i+1])
__global__ __launch_bounds__(1024) void k_scanC(
    int* __restrict__ cnt, const int* __restrict__ bsum, int* __restrict__ rowptr) {
  __shared__ int wsum[16];
  __shared__ int boff_s;
  const int t = threadIdx.x, lane = t & 63, wid = t >> 6;
  if (t < 64) {
    int v = (t < blockIdx.x) ? bsum[t] : 0;
    #pragma unroll
    for (int m = 1; m <= 32; m <<= 1) v += __shfl_xor(v, m);
    if (t == 0) boff_s = v;
  }
  const int i = blockIdx.x * 1024 + t;
  const int val = (i < NN) ? cnt[i] : 0;
  int incl = val;
  #pragma unroll
  for (int off = 1; off < 64; off <<= 1) {
    int n = __shfl_up(incl, off, 64);
    if (lane >= off) incl += n;
  }
  if (lane == 63) wsum[wid] = incl;
  __syncthreads();
  if (t < 16) {
    int wv = wsum[t];
    int wincl = wv;
    #pragma unroll
    for (int off = 1; off < 16; off <<= 1) {
      int n = __shfl_up(wincl, off, 64);
      if (t >= off) wincl += n;
    }
    wsum[t] = wincl - wv;
  }
  __syncthreads();
  if (i < NN) {
    const int inc_g = boff_s + wsum[wid] + incl;   // inclusive global
    rowptr[i] = inc_g - val;                        // exclusive
    cnt[i]    = inc_g;                              // = rowptr[i+1], consumed by fill
  }
  if (blockIdx.x == 0 && t == 0) rowptr[NN] = NE;
}

// ---------------- S3: bucket-fill, 4B records {src:16 | ea_fp16:16} ---------
// atomicSub(cnt) yields the absolute slot directly (cnt holds rowptr[i+1])
__global__ __launch_bounds__(256) void k_fill(
    const int* __restrict__ ei, const float* __restrict__ ea,
    int* __restrict__ cnt, unsigned* __restrict__ epk) {
  const int e = blockIdx.x * 256 + threadIdx.x;
  if (e < NE) {
    const int dst = ei[NE + e];
    const int idx = atomicSub(&cnt[dst], 1) - 1;
    const unsigned rec = (unsigned)ei[e] |
        ((unsigned)__half_as_ushort(__float2half_rn(ea[e])) << 16);
    epk[idx] = rec;
  }
}

// ------- K2: per-dst softmax + agg (fp8 kv, DPP reduce, 8-edge unroll),
//         single barrier after wlT staging; waves independent afterwards -----
__global__ __launch_bounds__(256) void k_fused(
    const float* __restrict__ qs, const unsigned* __restrict__ kvp,
    const float* __restrict__ skip, const float* __restrict__ x,
    const int* __restrict__ rowptr, const unsigned* __restrict__ epk,
    const float* __restrict__ We,
    const float* __restrict__ Wl, const float* __restrict__ bl,
    const float* __restrict__ g0, const float* __restrict__ b0,
    const float* __restrict__ g1, const float* __restrict__ b1,
    float* __restrict__ out)
{
  __shared__ float wlT[64][65];   // wlT[k][j] = Wl[j][k]
  __shared__ float scx[4][64];    // per-wave scratch (transpose + x1 broadcast)
  const int t = threadIdx.x;
  {
    const int jl = t >> 2, c0 = (t & 3) * 16;
    const float4* wr = (const float4*)(Wl + (size_t)jl * 64 + c0);
    float4 w0 = wr[0], w1 = wr[1], w2 = wr[2], w3 = wr[3];
    wlT[c0 +  0][jl] = w0.x; wlT[c0 +  1][jl] = w0.y; wlT[c0 +  2][jl] = w0.z; wlT[c0 +  3][jl] = w0.w;
    wlT[c0 +  4][jl] = w1.x; wlT[c0 +  5][jl] = w1.y; wlT[c0 +  6][jl] = w1.z; wlT[c0 +  7][jl] = w1.w;
    wlT[c0 +  8][jl] = w2.x; wlT[c0 +  9][jl] = w2.y; wlT[c0 + 10][jl] = w2.z; wlT[c0 + 11][jl] = w2.w;
    wlT[c0 + 12][jl] = w3.x; wlT[c0 + 13][jl] = w3.y; wlT[c0 + 14][jl] = w3.z; wlT[c0 + 15][jl] = w3.w;
  }
  __syncthreads();  // the ONLY barrier; all cross-wave LDS (wlT) ready here

  const int w = t >> 6;
  const int dst = __builtin_amdgcn_readfirstlane(blockIdx.x * 4 + w);
  const int lane = t & 63;
  const int half = lane >> 5;
  const int el = lane & 31;

  const float4 qv = ((const float4*)(qs + (size_t)dst * 128))[el];
  const float4 we4 = ((const float4*)We)[el];
  const float skipv = skip[(size_t)dst * 64 + lane];
  const float xv    = x[(size_t)dst * 64 + lane];

  const float qwe = red16(qv.x * we4.x + qv.y * we4.y + qv.z * we4.z + qv.w * we4.w);

  const int base = rowptr[dst];
  const int deg  = rowptr[dst + 1] - base;
  const uint2* kv8 = (const uint2*)kvp;
  const unsigned* ep = epk + base;

  float s = 0.f, sw = 0.f;
  float sv0 = 0.f, sv1 = 0.f, sv2 = 0.f, sv3 = 0.f;

  const float SCL = 0.18033688011112042f;  // 0.125*log2(e)

#define UNPACK_W(er) __half2float(__ushort_as_half((unsigned short)((er) >> 16)))
#define PROC(u, wg, mask)                                                   \
  {                                                                         \
    const v2f k01 = __builtin_amdgcn_cvt_pk_f32_fp8((u).x, false);          \
    const v2f k23 = __builtin_amdgcn_cvt_pk_f32_fp8((u).x, true);           \
    const v2f v01 = __builtin_amdgcn_cvt_pk_f32_fp8((u).y, false);          \
    const v2f v23 = __builtin_amdgcn_cvt_pk_f32_fp8((u).y, true);           \
    const float p = red16(qv.x * k01.x + qv.y * k01.y +                     \
                          qv.z * k23.x + qv.w * k23.y);                     \
    float e_ = exp2f((p + (wg) * qwe) * SCL);                               \
    e_ = (mask) ? e_ : 0.f;                                                 \
    s += e_; sw += e_ * (wg);                                               \
    sv0 += e_ * v01.x; sv1 += e_ * v01.y;                                   \
    sv2 += e_ * v23.x; sv3 += e_ * v23.y;                                   \
  }

  int i = 0;
  for (; i + 8 <= deg; i += 8) {
    const unsigned er0 = ep[i + half];
    const unsigned er1 = ep[i + 2 + half];
    const unsigned er2 = ep[i + 4 + half];
    const unsigned er3 = ep[i + 6 + half];
    const uint2 u0 = kv8[(size_t)(er0 & 0xFFFFu) * 32 + el];
    const uint2 u1 = kv8[(size_t)(er1 & 0xFFFFu) * 32 + el];
    const uint2 u2 = kv8[(size_t)(er2 & 0xFFFFu) * 32 + el];
    const uint2 u3 = kv8[(size_t)(er3 & 0xFFFFu) * 32 + el];
    PROC(u0, UNPACK_W(er0), true)
    PROC(u1, UNPACK_W(er1), true)
    PROC(u2, UNPACK_W(er2), true)
    PROC(u3, UNPACK_W(er3), true)
  }
  for (; i + 4 <= deg; i += 4) {
    const unsigned er0 = ep[i + half];
    const unsigned er1 = ep[i + 2 + half];
    const uint2 u0 = kv8[(size_t)(er0 & 0xFFFFu) * 32 + el];
    const uint2 u1 = kv8[(size_t)(er1 & 0xFFFFu) * 32 + el];
    PROC(u0, UNPACK_W(er0), true)
    PROC(u1, UNPACK_W(er1), true)
  }
  for (; i < deg; i += 2) {
    const int idx = i + half;
    const bool valid = idx < deg;
    const unsigned er = ep[valid ? idx : (deg - 1)];
    const uint2 u = kv8[(size_t)(er & 0xFFFFu) * 32 + el];
    PROC(u, UNPACK_W(er), valid)
  }
#undef PROC
#undef UNPACK_W

  // combine the two half-wave partial accumulators
  s  += __shfl_xor(s, 32);
  sw += __shfl_xor(sw, 32);
  sv0 += __shfl_xor(sv0, 32); sv1 += __shfl_xor(sv1, 32);
  sv2 += __shfl_xor(sv2, 32); sv3 += __shfl_xor(sv3, 32);

  float a0 = 0.f, a1 = 0.f, a2 = 0.f, a3 = 0.f;
  if (deg > 0) {
    const float inv = 1.f / s;
    a0 = (sv0 + sw * we4.x) * inv;
    a1 = (sv1 + sw * we4.y) * inv;
    a2 = (sv2 + sw * we4.z) * inv;
    a3 = (sv3 + sw * we4.w) * inv;
  }
  a0 = 0.5f * (a0 + __shfl_xor(a0, 16));
  a1 = 0.5f * (a1 + __shfl_xor(a1, 16));
  a2 = 0.5f * (a2 + __shfl_xor(a2, 16));
  a3 = 0.5f * (a3 + __shfl_xor(a3, 16));
  if (half == 0 && el < 16) {
    ((float4*)scx[w])[el] = make_float4(a0, a1, a2, a3);
  }
  // intra-wave LDS dependency only — no barrier needed
  const float hv = scx[w][lane] + skipv;

  // LN0 via dual moments (DPP + 2 shfl each, independent chains)
  float m1 = hv, m2 = hv * hv;
  m1 = red16(m1); m2 = red16(m2);
  m1 += __shfl_xor(m1, 16); m2 += __shfl_xor(m2, 16);
  m1 += __shfl_xor(m1, 32); m2 += __shfl_xor(m2, 32);
  const float mean = m1 * (1.f / 64.f);
  const float var = fmaxf(m2 * (1.f / 64.f) - mean * mean, 0.f);
  const float x1 = xv + (hv - mean) * rsqrtf(var + 1e-5f) * g0[lane] + b0[lane];

  // broadcast x1 row through per-wave LDS, then y = x1 @ Wl^T + bl
  scx[w][lane] = x1;
  float y0 = 0.f, y1 = 0.f, y2 = 0.f, y3 = 0.f;
  #pragma unroll
  for (int kk = 0; kk < 64; kk += 4) {
    const float4 xb = *(const float4*)&scx[w][kk];   // uniform -> broadcast
    y0 += xb.x * wlT[kk][lane];
    y1 += xb.y * wlT[kk + 1][lane];
    y2 += xb.z * wlT[kk + 2][lane];
    y3 += xb.w * wlT[kk + 3][lane];
  }
  const float y = bl[lane] + (y0 + y1) + (y2 + y3);

  // LN1 via dual moments
  float n1 = y, n2 = y * y;
  n1 = red16(n1); n2 = red16(n2);
  n1 += __shfl_xor(n1, 16); n2 += __shfl_xor(n2, 16);
  n1 += __shfl_xor(n1, 32); n2 += __shfl_xor(n2, 32);
  const float mean2 = n1 * (1.f / 64.f);
  const float var2 = fmaxf(n2 * (1.f / 64.f) - mean2 * mean2, 0.f);
  out[(size_t)dst * 64 + lane] = x1 + (y - mean2) * rsqrtf(var2 + 1e-5f) * g1[lane] + b1[lane];
}

extern "C" void kernel_launch(void* const* d_in, const int* in_sizes, int n_in,
                              void* d_out, int out_size, void* d_ws, size_t ws_size,
                              hipStream_t stream) {
  const float* x     = (const float*)d_in[0];
  const int*   ei    = (const int*)d_in[1];
  const float* ea    = (const float*)d_in[2];
  const float* Wq    = (const float*)d_in[3];
  const float* bq    = (const float*)d_in[4];
  const float* Wk    = (const float*)d_in[5];
  const float* bk    = (const float*)d_in[6];
  const float* Wv    = (const float*)d_in[7];
  const float* bv    = (const float*)d_in[8];
  const float* We    = (const float*)d_in[9];
  const float* Wskip = (const float*)d_in[10];
  const float* bskip = (const float*)d_in[11];
  const float* Wl    = (const float*)d_in[12];
  const float* bl    = (const float*)d_in[13];
  const float* g0    = (const float*)d_in[14];
  const float* b0    = (const float*)d_in[15];
  const float* g1    = (const float*)d_in[16];
  const float* b1    = (const float*)d_in[17];
  float* out = (float*)d_out;

  float* ws = (float*)d_ws;
  size_t off = 0;
  float* qs   = ws + off; off += (size_t)NN * 128;
  unsigned* kvp = (unsigned*)(ws + off); off += (size_t)NN * 64;  // 256B/node fp8
  float* skip = ws + off; off += (size_t)NN * 64;
  int* cnt    = (int*)(ws + off); off += NN;
  int* rowptr = (int*)(ws + off); off += NN + 1;
  int* bsum   = (int*)(ws + off); off += 64;
  unsigned* epk = (unsigned*)(ws + off); off += NE;

  (void)hipMemsetAsync(cnt, 0, (size_t)NN * sizeof(int), stream);

  dim3 gGemm((NN + 63) / 64, 2);  // y==1 -> histogram slice
  hipLaunchKernelGGL(k_gemm_qkv, gGemm, dim3(256), 0, stream,
                     x, Wq, bq, Wk, bk, Wv, bv, Wskip, bskip, ei, cnt, qs, kvp, skip);
  hipLaunchKernelGGL(k_scanA, dim3(49), dim3(1024), 0, stream, cnt, bsum);
  hipLaunchKernelGGL(k_scanC, dim3(49), dim3(1024), 0, stream, cnt, bsum, rowptr);
  hipLaunchKernelGGL(k_fill, dim3((NE + 255) / 256), dim3(256), 0, stream,
                     ei, ea, cnt, epk);
  hipLaunchKernelGGL(k_fused, dim3(NN / 4), dim3(256), 0, stream,
                     qs, kvp, skip, x, rowptr, epk, We,
                     Wl, bl, g0, b0, g1, b1, out);
}